// Round 1
// baseline (562.308 us; speedup 1.0000x reference)
//
#include <hip/hip_runtime.h>

#define N_NODES  50000
#define N_EDGESC 1600000
#define N_GRAPHS 64

static __device__ __forceinline__ int lowerb(const int* a, int n, int v) {
  int lo = 0, hi = n;
  while (lo < hi) { int m = (lo + hi) >> 1; if (a[m] < v) lo = m + 1; else hi = m; }
  return lo;
}

__global__ void k_count(const int* __restrict__ dst, int* __restrict__ cnt, int E) {
  int e = blockIdx.x * blockDim.x + threadIdx.x;
  if (e < E) atomicAdd(&cnt[dst[e]], 1);
}

// per-block exclusive scan (256 elems) + block sums
__global__ void k_scan1(const int* __restrict__ cnt, int* __restrict__ row_off,
                        int* __restrict__ bsums, int n_elems, int N) {
  __shared__ int sm[256];
  int t = threadIdx.x;
  int gid = blockIdx.x * 256 + t;
  int v = (gid < N) ? cnt[gid] : 0;
  sm[t] = v;
  __syncthreads();
  for (int off = 1; off < 256; off <<= 1) {
    int add = (t >= off) ? sm[t - off] : 0;
    __syncthreads();
    sm[t] += add;
    __syncthreads();
  }
  if (gid < n_elems) row_off[gid] = sm[t] - v;   // exclusive within block
  if (t == 255) bsums[blockIdx.x] = sm[t];       // block total
}

__global__ void k_scan2(int* __restrict__ bsums, int nb) {
  __shared__ int sm[256];
  int t = threadIdx.x;
  int v = (t < nb) ? bsums[t] : 0;
  sm[t] = v;
  __syncthreads();
  for (int off = 1; off < 256; off <<= 1) {
    int add = (t >= off) ? sm[t - off] : 0;
    __syncthreads();
    sm[t] += add;
    __syncthreads();
  }
  if (t < nb) bsums[t] = sm[t] - v;              // exclusive block offsets
}

__global__ void k_scan3(int* __restrict__ row_off, const int* __restrict__ bsums, int n_elems) {
  int gid = blockIdx.x * 256 + threadIdx.x;
  if (gid < n_elems) row_off[gid] += bsums[blockIdx.x];
}

__global__ void k_fill(const int* __restrict__ src, const int* __restrict__ dst,
                       const int* __restrict__ row_off, int* __restrict__ cur,
                       int* __restrict__ csr_src, int E) {
  int e = blockIdx.x * blockDim.x + threadIdx.x;
  if (e < E) {
    int d = dst[e];
    int p = row_off[d] + atomicAdd(&cur[d], 1);
    csr_src[p] = src[e];
  }
}

__global__ void k_dinv(const int* __restrict__ cnt, float* __restrict__ dinv, int N) {
  int i = blockIdx.x * blockDim.x + threadIdx.x;
  if (i < N) dinv[i] = rsqrtf((float)(cnt[i] + 1));  // +1 self-loop, deg >= 1 always
}

// out[i][c] = (x[i,:] @ W[:,c]) * dinv[i]   (row-prescaled features)
template <int K>
__global__ __launch_bounds__(256) void k_gemm(const float* __restrict__ x,
                                              const float* __restrict__ W,
                                              const float* __restrict__ dinv,
                                              float* __restrict__ out, int N) {
  __shared__ float Wl[K * 64];
  for (int idx = threadIdx.x; idx < K * 64; idx += 256) Wl[idx] = W[idx];
  __syncthreads();
  int c = threadIdx.x & 63;
  int wid = blockIdx.x * 4 + (threadIdx.x >> 6);
  int stride = gridDim.x * 4;
  for (int i = wid; i < N; i += stride) {
    const float* xr = x + (size_t)i * K;
    float acc = 0.f;
#pragma unroll
    for (int k = 0; k < K; k += 4) {
      float4 xv = *reinterpret_cast<const float4*>(xr + k);   // wave-broadcast 16B load
      acc += xv.x * Wl[(k + 0) * 64 + c];
      acc += xv.y * Wl[(k + 1) * 64 + c];
      acc += xv.z * Wl[(k + 2) * 64 + c];
      acc += xv.w * Wl[(k + 3) * 64 + c];
    }
    out[(size_t)i * 64 + c] = acc * dinv[i];
  }
}

// out[i][c] = relu( dinv[i]*(hs[i][c] + sum_{s in nbr(i)} hs[s][c]) + bias[c] )
__global__ __launch_bounds__(256) void k_gather(const float* __restrict__ hs,
                                                const int* __restrict__ row_off,
                                                const int* __restrict__ csr_src,
                                                const float* __restrict__ dinv,
                                                const float* __restrict__ bias,
                                                float* __restrict__ out, int N) {
  int c = threadIdx.x & 63;
  int wid = blockIdx.x * 4 + (threadIdx.x >> 6);
  int stride = gridDim.x * 4;
  for (int i = wid; i < N; i += stride) {
    float acc = hs[(size_t)i * 64 + c];            // self-loop term
    int s0 = row_off[i], s1 = row_off[i + 1];
    for (int base = s0; base < s1; base += 64) {
      int e = base + c;
      int ms = (e < s1) ? csr_src[e] : 0;          // coalesced edge-index load
      int n = s1 - base; if (n > 64) n = 64;
#pragma unroll 4
      for (int j = 0; j < n; ++j) {
        int s = __shfl(ms, j);                     // broadcast src index
        acc += hs[(size_t)s * 64 + c];             // coalesced 256B row read
      }
    }
    out[(size_t)i * 64 + c] = fmaxf(fmaf(acc, dinv[i], bias[c]), 0.0f);
  }
}

__global__ void k_pool(const float* __restrict__ h, const int* __restrict__ batch,
                       float* __restrict__ gmean, int N) {
  int g = blockIdx.x;
  int lo = lowerb(batch, N, g);
  int hi = lowerb(batch, N, g + 1);
  int w = threadIdx.x >> 6, c = threadIdx.x & 63;
  float acc = 0.f;
  for (int i = lo + w; i < hi; i += 4) acc += h[(size_t)i * 64 + c];
  __shared__ float sm[4][64];
  sm[w][c] = acc;
  __syncthreads();
  if (w == 0) {
    float s = sm[0][c] + sm[1][c] + sm[2][c] + sm[3][c];
    float n = (float)(hi - lo);
    gmean[g * 64 + c] = s / fmaxf(n, 1.0f);
  }
}

__global__ void k_final(const float* __restrict__ gmean, const float* __restrict__ Wp,
                        const float* __restrict__ bp, float* __restrict__ out) {
  int idx = blockIdx.x * 256 + threadIdx.x;  // < 4096
  int g = idx >> 6, o = idx & 63;
  float acc = bp[o];
#pragma unroll
  for (int k = 0; k < 64; ++k) acc += gmean[g * 64 + k] * Wp[k * 64 + o];
  out[idx] = acc;
}

extern "C" void kernel_launch(void* const* d_in, const int* in_sizes, int n_in,
                              void* d_out, int out_size, void* d_ws, size_t ws_size,
                              hipStream_t stream) {
  const float* x    = (const float*)d_in[0];
  const float* W1   = (const float*)d_in[1];
  const float* b1   = (const float*)d_in[2];
  const float* W2   = (const float*)d_in[3];
  const float* b2   = (const float*)d_in[4];
  const float* Wp   = (const float*)d_in[5];
  const float* bp   = (const float*)d_in[6];
  const int*   ei   = (const int*)d_in[7];
  const int*   batch= (const int*)d_in[8];
  float* out = (float*)d_out;

  const int N = N_NODES, E = N_EDGESC;
  const int* src  = ei;        // edge_index[0]
  const int* dstp = ei + E;    // edge_index[1]

  char* wsb = (char*)d_ws;
  size_t o = 0;
  auto alloc = [&](size_t bytes) -> void* {
    void* p = wsb + o;
    o = (o + bytes + 255) & ~(size_t)255;
    return p;
  };
  int*   cnt     = (int*)alloc((size_t)N * 4);
  int*   cur     = (int*)alloc((size_t)N * 4);
  int*   row_off = (int*)alloc((size_t)(N + 1) * 4);
  int*   csr     = (int*)alloc((size_t)E * 4);
  int*   bsums   = (int*)alloc(256 * 4);
  float* dinv    = (float*)alloc((size_t)N * 4);
  float* bufA    = (float*)alloc((size_t)N * 64 * 4);
  float* bufB    = (float*)alloc((size_t)N * 64 * 4);
  float* gmean   = (float*)alloc(64 * 64 * 4);

  hipMemsetAsync(cnt, 0, (size_t)N * 4, stream);
  hipMemsetAsync(cur, 0, (size_t)N * 4, stream);

  int gE = (E + 255) / 256;
  int NB = (N + 1 + 255) / 256;  // 196

  k_count<<<gE, 256, 0, stream>>>(dstp, cnt, E);
  k_scan1<<<NB, 256, 0, stream>>>(cnt, row_off, bsums, N + 1, N);
  k_scan2<<<1, 256, 0, stream>>>(bsums, NB);
  k_scan3<<<NB, 256, 0, stream>>>(row_off, bsums, N + 1);
  k_fill<<<gE, 256, 0, stream>>>(src, dstp, row_off, cur, csr, E);
  k_dinv<<<(N + 255) / 256, 256, 0, stream>>>(cnt, dinv, N);

  k_gemm<128><<<2048, 256, 0, stream>>>(x, W1, dinv, bufA, N);
  k_gather<<<2048, 256, 0, stream>>>(bufA, row_off, csr, dinv, b1, bufB, N);
  k_gemm<64><<<2048, 256, 0, stream>>>(bufB, W2, dinv, bufA, N);
  k_gather<<<2048, 256, 0, stream>>>(bufA, row_off, csr, dinv, b2, bufB, N);

  k_pool<<<N_GRAPHS, 256, 0, stream>>>(bufB, batch, gmean, N);
  k_final<<<16, 256, 0, stream>>>(gmean, Wp, bp, out);
}

// Round 2
// 485.313 us; speedup vs baseline: 1.1587x; 1.1587x over previous
//
#include <hip/hip_runtime.h>

#define N_NODES  50000
#define N_EDGESC 1600000
#define N_GRAPHS 64

static __device__ __forceinline__ int lowerb(const int* a, int n, int v) {
  int lo = 0, hi = n;
  while (lo < hi) { int m = (lo + hi) >> 1; if (a[m] < v) lo = m + 1; else hi = m; }
  return lo;
}

__global__ void k_count(const int* __restrict__ dst, int* __restrict__ cnt, int E) {
  int e = blockIdx.x * blockDim.x + threadIdx.x;
  if (e < E) atomicAdd(&cnt[dst[e]], 1);
}

// per-block exclusive scan (256 elems) + block sums
__global__ void k_scan1(const int* __restrict__ cnt, int* __restrict__ row_off,
                        int* __restrict__ bsums, int n_elems, int N) {
  __shared__ int sm[256];
  int t = threadIdx.x;
  int gid = blockIdx.x * 256 + t;
  int v = (gid < N) ? cnt[gid] : 0;
  sm[t] = v;
  __syncthreads();
  for (int off = 1; off < 256; off <<= 1) {
    int add = (t >= off) ? sm[t - off] : 0;
    __syncthreads();
    sm[t] += add;
    __syncthreads();
  }
  if (gid < n_elems) row_off[gid] = sm[t] - v;   // exclusive within block
  if (t == 255) bsums[blockIdx.x] = sm[t];       // block total
}

__global__ void k_scan2(int* __restrict__ bsums, int nb) {
  __shared__ int sm[256];
  int t = threadIdx.x;
  int v = (t < nb) ? bsums[t] : 0;
  sm[t] = v;
  __syncthreads();
  for (int off = 1; off < 256; off <<= 1) {
    int add = (t >= off) ? sm[t - off] : 0;
    __syncthreads();
    sm[t] += add;
    __syncthreads();
  }
  if (t < nb) bsums[t] = sm[t] - v;              // exclusive block offsets
}

__global__ void k_scan3(int* __restrict__ row_off, const int* __restrict__ bsums, int n_elems) {
  int gid = blockIdx.x * 256 + threadIdx.x;
  if (gid < n_elems) row_off[gid] += bsums[blockIdx.x];
}

__global__ void k_fill(const int* __restrict__ src, const int* __restrict__ dst,
                       const int* __restrict__ row_off, int* __restrict__ cur,
                       int* __restrict__ csr_src, int E) {
  int e = blockIdx.x * blockDim.x + threadIdx.x;
  if (e < E) {
    int d = dst[e];
    int p = row_off[d] + atomicAdd(&cur[d], 1);
    csr_src[p] = src[e];
  }
}

__global__ void k_dinv(const int* __restrict__ cnt, float* __restrict__ dinv, int N) {
  int i = blockIdx.x * blockDim.x + threadIdx.x;
  if (i < N) dinv[i] = rsqrtf((float)(cnt[i] + 1));  // +1 self-loop, deg >= 1 always
}

// out[i][c] = (x[i,:] @ W[:,c]) * dinv[i]   (row-prescaled features)
// lane = node (64-node tile/block). x staged in LDS (pad K+1 -> conflict-free
// b32 reads). W[k*64+j] is wave-uniform -> s_load into SGPRs, FMA operand.
// acc[64] channels per lane; transpose via LDS for coalesced stores.
template <int K>
__global__ __launch_bounds__(64) void k_gemm(const float* __restrict__ x,
                                             const float* __restrict__ W,
                                             const float* __restrict__ dinv,
                                             float* __restrict__ out, int N) {
  constexpr int KP = K + 1;
  __shared__ float xs[64 * KP];   // K=128: 33KB -> 4 blocks/CU; K=64: 16.6KB
  const int lane = threadIdx.x;
  const int n0 = blockIdx.x * 64;

  // stage x tile, coalesced float4 loads (32 threads cover one row of 128)
  constexpr int NF4 = K / 4;             // float4 per row
  constexpr int ITERS = 64 * NF4 / 64;   // per-thread float4 count
#pragma unroll 4
  for (int it = 0; it < ITERS; ++it) {
    int li = it * 64 + lane;
    int row = li / NF4;
    int c4 = li % NF4;
    int node = n0 + row;
    float4 v = make_float4(0.f, 0.f, 0.f, 0.f);
    if (node < N) v = *reinterpret_cast<const float4*>(x + (size_t)node * K + c4 * 4);
    float* dp = xs + row * KP + c4 * 4;
    dp[0] = v.x; dp[1] = v.y; dp[2] = v.z; dp[3] = v.w;
  }
  __syncthreads();

  float acc[64];
#pragma unroll
  for (int c = 0; c < 64; ++c) acc[c] = 0.f;

  const float* xr = xs + lane * KP;
#pragma unroll 2
  for (int k = 0; k < K; ++k) {
    float xv = xr[k];                                        // conflict-free LDS
    const float4* wr = reinterpret_cast<const float4*>(W + k * 64);  // uniform
#pragma unroll
    for (int j = 0; j < 16; ++j) {
      float4 w = wr[j];                                      // s_load (SGPR)
      acc[4 * j + 0] = fmaf(xv, w.x, acc[4 * j + 0]);
      acc[4 * j + 1] = fmaf(xv, w.y, acc[4 * j + 1]);
      acc[4 * j + 2] = fmaf(xv, w.z, acc[4 * j + 2]);
      acc[4 * j + 3] = fmaf(xv, w.w, acc[4 * j + 3]);
    }
  }

  int node = n0 + lane;
  float dv = (node < N) ? dinv[node] : 0.f;

  // transpose through LDS for coalesced stores (reuse xs; need 64*65 <= 64*KP)
  __syncthreads();
#pragma unroll
  for (int c = 0; c < 64; ++c) xs[lane * 65 + c] = acc[c] * dv;
  __syncthreads();
#pragma unroll
  for (int it = 0; it < 16; ++it) {
    int f4 = it * 64 + lane;        // float4 index over 64x64 tile
    int nd = f4 >> 4;               // node within tile
    int c4 = f4 & 15;
    if (n0 + nd < N) {
      const float* sp = xs + nd * 65 + c4 * 4;
      float4 v = make_float4(sp[0], sp[1], sp[2], sp[3]);
      *reinterpret_cast<float4*>(out + (size_t)(n0 + nd) * 64 + c4 * 4) = v;
    }
  }
}

// out[i][c] = relu( dinv[i]*(hs[i][c] + sum_{s in nbr(i)} hs[s][c]) + bias[c] )
__global__ __launch_bounds__(256) void k_gather(const float* __restrict__ hs,
                                                const int* __restrict__ row_off,
                                                const int* __restrict__ csr_src,
                                                const float* __restrict__ dinv,
                                                const float* __restrict__ bias,
                                                float* __restrict__ out, int N) {
  int c = threadIdx.x & 63;
  int wid = blockIdx.x * 4 + (threadIdx.x >> 6);
  int stride = gridDim.x * 4;
  for (int i = wid; i < N; i += stride) {
    float acc = hs[(size_t)i * 64 + c];            // self-loop term
    int s0 = row_off[i], s1 = row_off[i + 1];
    for (int base = s0; base < s1; base += 64) {
      int e = base + c;
      int ms = (e < s1) ? csr_src[e] : 0;          // coalesced edge-index load
      int n = s1 - base; if (n > 64) n = 64;
#pragma unroll 4
      for (int j = 0; j < n; ++j) {
        int s = __shfl(ms, j);                     // broadcast src index
        acc += hs[(size_t)s * 64 + c];             // coalesced 256B row read
      }
    }
    out[(size_t)i * 64 + c] = fmaxf(fmaf(acc, dinv[i], bias[c]), 0.0f);
  }
}

__global__ void k_pool(const float* __restrict__ h, const int* __restrict__ batch,
                       float* __restrict__ gmean, int N) {
  int g = blockIdx.x;
  int lo = lowerb(batch, N, g);
  int hi = lowerb(batch, N, g + 1);
  int w = threadIdx.x >> 6, c = threadIdx.x & 63;
  float acc = 0.f;
  for (int i = lo + w; i < hi; i += 4) acc += h[(size_t)i * 64 + c];
  __shared__ float sm[4][64];
  sm[w][c] = acc;
  __syncthreads();
  if (w == 0) {
    float s = sm[0][c] + sm[1][c] + sm[2][c] + sm[3][c];
    float n = (float)(hi - lo);
    gmean[g * 64 + c] = s / fmaxf(n, 1.0f);
  }
}

__global__ void k_final(const float* __restrict__ gmean, const float* __restrict__ Wp,
                        const float* __restrict__ bp, float* __restrict__ out) {
  int idx = blockIdx.x * 256 + threadIdx.x;  // < 4096
  int g = idx >> 6, o = idx & 63;
  float acc = bp[o];
#pragma unroll
  for (int k = 0; k < 64; ++k) acc += gmean[g * 64 + k] * Wp[k * 64 + o];
  out[idx] = acc;
}

extern "C" void kernel_launch(void* const* d_in, const int* in_sizes, int n_in,
                              void* d_out, int out_size, void* d_ws, size_t ws_size,
                              hipStream_t stream) {
  const float* x    = (const float*)d_in[0];
  const float* W1   = (const float*)d_in[1];
  const float* b1   = (const float*)d_in[2];
  const float* W2   = (const float*)d_in[3];
  const float* b2   = (const float*)d_in[4];
  const float* Wp   = (const float*)d_in[5];
  const float* bp   = (const float*)d_in[6];
  const int*   ei   = (const int*)d_in[7];
  const int*   batch= (const int*)d_in[8];
  float* out = (float*)d_out;

  const int N = N_NODES, E = N_EDGESC;
  const int* src  = ei;        // edge_index[0]
  const int* dstp = ei + E;    // edge_index[1]

  char* wsb = (char*)d_ws;
  size_t o = 0;
  auto alloc = [&](size_t bytes) -> void* {
    void* p = wsb + o;
    o = (o + bytes + 255) & ~(size_t)255;
    return p;
  };
  int*   cnt     = (int*)alloc((size_t)N * 4);
  int*   cur     = (int*)alloc((size_t)N * 4);
  int*   row_off = (int*)alloc((size_t)(N + 1) * 4);
  int*   csr     = (int*)alloc((size_t)E * 4);
  int*   bsums   = (int*)alloc(256 * 4);
  float* dinv    = (float*)alloc((size_t)N * 4);
  float* bufA    = (float*)alloc((size_t)N * 64 * 4);
  float* bufB    = (float*)alloc((size_t)N * 64 * 4);
  float* gmean   = (float*)alloc(64 * 64 * 4);

  hipMemsetAsync(cnt, 0, (size_t)N * 4, stream);
  hipMemsetAsync(cur, 0, (size_t)N * 4, stream);

  int gE = (E + 255) / 256;
  int NB = (N + 1 + 255) / 256;  // 196
  int gN64 = (N + 63) / 64;      // 782

  k_count<<<gE, 256, 0, stream>>>(dstp, cnt, E);
  k_scan1<<<NB, 256, 0, stream>>>(cnt, row_off, bsums, N + 1, N);
  k_scan2<<<1, 256, 0, stream>>>(bsums, NB);
  k_scan3<<<NB, 256, 0, stream>>>(row_off, bsums, N + 1);
  k_fill<<<gE, 256, 0, stream>>>(src, dstp, row_off, cur, csr, E);
  k_dinv<<<(N + 255) / 256, 256, 0, stream>>>(cnt, dinv, N);

  k_gemm<128><<<gN64, 64, 0, stream>>>(x, W1, dinv, bufA, N);
  k_gather<<<2048, 256, 0, stream>>>(bufA, row_off, csr, dinv, b1, bufB, N);
  k_gemm<64><<<gN64, 64, 0, stream>>>(bufB, W2, dinv, bufA, N);
  k_gather<<<2048, 256, 0, stream>>>(bufA, row_off, csr, dinv, b2, bufB, N);

  k_pool<<<N_GRAPHS, 256, 0, stream>>>(bufB, batch, gmean, N);
  k_final<<<16, 256, 0, stream>>>(gmean, Wp, bp, out);
}

// Round 3
// 400.982 us; speedup vs baseline: 1.4023x; 1.2103x over previous
//
#include <hip/hip_runtime.h>

#define N_NODES  50000
#define N_EDGESC 1600000
#define N_GRAPHS 64
#define NBUCK    196      // ceil(50000/256) buckets of 256 dst nodes
#define BCAP     10240    // >> E/NBUCK (8163) + 20σ; overflow prob ~0
#define CHUNK    8192     // edges per bucketing block

static __device__ __forceinline__ unsigned short f2bf(float f) {
  unsigned u = __float_as_uint(f);
  u += 0x7FFF + ((u >> 16) & 1);          // RNE
  return (unsigned short)(u >> 16);
}
static __device__ __forceinline__ float bf2f(unsigned short u) {
  return __uint_as_float(((unsigned)u) << 16);
}

static __device__ __forceinline__ int lowerb(const int* a, int n, int v) {
  int lo = 0, hi = n;
  while (lo < hi) { int m = (lo + hi) >> 1; if (a[m] < v) lo = m + 1; else hi = m; }
  return lo;
}

// Phase A: chunk-bucket edges by dst>>8; per-(block,bucket) runs are
// sequential -> mostly full-line writes. Entry packed (local_dst<<24)|src.
__global__ __launch_bounds__(256) void k_bucket(const int* __restrict__ src,
                                                const int* __restrict__ dst,
                                                int* __restrict__ gcur,
                                                unsigned* __restrict__ bbuf, int E) {
  __shared__ int hist[NBUCK], base[NBUCK], cur[NBUCK];
  int t = threadIdx.x;
  if (t < NBUCK) { hist[t] = 0; cur[t] = 0; }
  __syncthreads();
  int e0 = blockIdx.x * CHUNK;
  for (int i = 0; i < CHUNK; i += 256) {
    int e = e0 + i + t;
    if (e < E) atomicAdd(&hist[dst[e] >> 8], 1);
  }
  __syncthreads();
  if (t < NBUCK) base[t] = hist[t] ? atomicAdd(&gcur[t], hist[t]) : 0;
  __syncthreads();
  for (int i = 0; i < CHUNK; i += 256) {
    int e = e0 + i + t;
    if (e < E) {
      int d = dst[e], b = d >> 8;
      int pos = base[b] + atomicAdd(&cur[b], 1);
      unsigned packed = ((unsigned)(d & 255) << 24) | (unsigned)src[e];
      if (pos < BCAP) bbuf[(size_t)b * BCAP + pos] = packed;
    }
  }
}

// exclusive scan of the 196 bucket totals
__global__ void k_bscan(const int* __restrict__ gcur, int* __restrict__ boff) {
  __shared__ int sm[256];
  int t = threadIdx.x;
  int v = (t < NBUCK) ? gcur[t] : 0;
  sm[t] = v;
  __syncthreads();
  for (int o = 1; o < 256; o <<= 1) {
    int add = (t >= o) ? sm[t - o] : 0;
    __syncthreads();
    sm[t] += add;
    __syncthreads();
  }
  if (t < NBUCK) boff[t] = sm[t] - v;
}

// Phase B: per-bucket counting sort -> csr segment + row_off + dinv.
// Scatter confined to one block (one XCD) over a 32KB region -> L2-coalesced.
__global__ __launch_bounds__(256) void k_bsort(const unsigned* __restrict__ bbuf,
                                               const int* __restrict__ gcur,
                                               const int* __restrict__ boff,
                                               int* __restrict__ csr,
                                               int* __restrict__ row_off,
                                               float* __restrict__ dinv, int E) {
  __shared__ int hist[256], off[256], cur[256];
  int b = blockIdx.x, t = threadIdx.x;
  hist[t] = 0; cur[t] = 0;
  __syncthreads();
  int cnt = min(gcur[b], BCAP);
  const unsigned* bp = bbuf + (size_t)b * BCAP;
  for (int i = t; i < cnt; i += 256) atomicAdd(&hist[bp[i] >> 24], 1);
  __syncthreads();
  off[t] = hist[t];
  __syncthreads();
  for (int o = 1; o < 256; o <<= 1) {
    int add = (t >= o) ? off[t - o] : 0;
    __syncthreads();
    off[t] += add;
    __syncthreads();
  }
  int excl = off[t] - hist[t];
  __syncthreads();
  off[t] = excl;
  __syncthreads();
  int gb = boff[b];
  int idx = (b << 8) + t;
  if (idx <= N_NODES) row_off[idx] = gb + off[t];
  if (idx < N_NODES)  dinv[idx] = rsqrtf((float)(hist[t] + 1));  // +1 self-loop
  for (int i = t; i < cnt; i += 256) {
    unsigned v = bp[i];
    int ld = v >> 24;
    int pos = atomicAdd(&cur[ld], 1);
    csr[gb + off[ld] + pos] = (int)(v & 0xFFFFFFu);
  }
}

// out_bf16[i][c] = bf16( (x[i,:] @ W[:,c]) * dinv[i] )
// lane = node; x staged in LDS (pad K+1); W wave-uniform -> SGPR s_loads.
template <int K>
__global__ __launch_bounds__(64) void k_gemm(const float* __restrict__ x,
                                             const float* __restrict__ W,
                                             const float* __restrict__ dinv,
                                             unsigned short* __restrict__ out, int N) {
  constexpr int KP = K + 1;
  __shared__ float xs[64 * KP];
  const int lane = threadIdx.x;
  const int n0 = blockIdx.x * 64;

  constexpr int NF4 = K / 4;
  constexpr int ITERS = 64 * NF4 / 64;
#pragma unroll 4
  for (int it = 0; it < ITERS; ++it) {
    int li = it * 64 + lane;
    int row = li / NF4;
    int c4 = li % NF4;
    int node = n0 + row;
    float4 v = make_float4(0.f, 0.f, 0.f, 0.f);
    if (node < N) v = *reinterpret_cast<const float4*>(x + (size_t)node * K + c4 * 4);
    float* dp = xs + row * KP + c4 * 4;
    dp[0] = v.x; dp[1] = v.y; dp[2] = v.z; dp[3] = v.w;
  }
  __syncthreads();

  float acc[64];
#pragma unroll
  for (int c = 0; c < 64; ++c) acc[c] = 0.f;

  const float* xr = xs + lane * KP;
#pragma unroll 2
  for (int k = 0; k < K; ++k) {
    float xv = xr[k];
    const float4* wr = reinterpret_cast<const float4*>(W + k * 64);  // uniform
#pragma unroll
    for (int j = 0; j < 16; ++j) {
      float4 w = wr[j];
      acc[4 * j + 0] = fmaf(xv, w.x, acc[4 * j + 0]);
      acc[4 * j + 1] = fmaf(xv, w.y, acc[4 * j + 1]);
      acc[4 * j + 2] = fmaf(xv, w.z, acc[4 * j + 2]);
      acc[4 * j + 3] = fmaf(xv, w.w, acc[4 * j + 3]);
    }
  }

  int node = n0 + lane;
  float dv = (node < N) ? dinv[node] : 0.f;

  __syncthreads();
#pragma unroll
  for (int c = 0; c < 64; ++c) xs[lane * 65 + c] = acc[c] * dv;
  __syncthreads();
#pragma unroll
  for (int it = 0; it < 16; ++it) {
    int f4 = it * 64 + lane;
    int nd = f4 >> 4;
    int c4 = f4 & 15;
    if (n0 + nd < N) {
      const float* sp = xs + nd * 65 + c4 * 4;
      ushort4 u;
      u.x = f2bf(sp[0]); u.y = f2bf(sp[1]); u.z = f2bf(sp[2]); u.w = f2bf(sp[3]);
      *reinterpret_cast<ushort4*>(out + (size_t)(n0 + nd) * 64 + c4 * 4) = u;
    }
  }
}

// out[i][c] = relu( dinv[i]*(hs[i][c] + sum_{s} hs[s][c]) + bias[c] ), hs in bf16
__global__ __launch_bounds__(256) void k_gather(const unsigned short* __restrict__ hs,
                                                const int* __restrict__ row_off,
                                                const int* __restrict__ csr_src,
                                                const float* __restrict__ dinv,
                                                const float* __restrict__ bias,
                                                float* __restrict__ out, int N) {
  int c = threadIdx.x & 63;
  int wid = blockIdx.x * 4 + (threadIdx.x >> 6);
  int stride = gridDim.x * 4;
  float bc = bias[c];
  for (int i = wid; i < N; i += stride) {
    float acc = bf2f(hs[(size_t)i * 64 + c]);      // self-loop term
    int s0 = row_off[i], s1 = row_off[i + 1];
    for (int base = s0; base < s1; base += 64) {
      int e = base + c;
      int ms = (e < s1) ? __builtin_nontemporal_load(csr_src + e) : 0;
      int n = s1 - base; if (n > 64) n = 64;
#pragma unroll 4
      for (int j = 0; j < n; ++j) {
        int s = __shfl(ms, j);
        acc += bf2f(hs[(size_t)s * 64 + c]);       // 128B coalesced row read
      }
    }
    float r = fmaxf(fmaf(acc, dinv[i], bc), 0.0f);
    __builtin_nontemporal_store(r, out + (size_t)i * 64 + c);
  }
}

__global__ void k_pool(const float* __restrict__ h, const int* __restrict__ batch,
                       float* __restrict__ gmean, int N) {
  int g = blockIdx.x;
  int lo = lowerb(batch, N, g);
  int hi = lowerb(batch, N, g + 1);
  int w = threadIdx.x >> 6, c = threadIdx.x & 63;
  float acc = 0.f;
  for (int i = lo + w; i < hi; i += 4) acc += h[(size_t)i * 64 + c];
  __shared__ float sm[4][64];
  sm[w][c] = acc;
  __syncthreads();
  if (w == 0) {
    float s = sm[0][c] + sm[1][c] + sm[2][c] + sm[3][c];
    float n = (float)(hi - lo);
    gmean[g * 64 + c] = s / fmaxf(n, 1.0f);
  }
}

__global__ void k_final(const float* __restrict__ gmean, const float* __restrict__ Wp,
                        const float* __restrict__ bp, float* __restrict__ out) {
  int idx = blockIdx.x * 256 + threadIdx.x;
  int g = idx >> 6, o = idx & 63;
  float acc = bp[o];
#pragma unroll
  for (int k = 0; k < 64; ++k) acc += gmean[g * 64 + k] * Wp[k * 64 + o];
  out[idx] = acc;
}

extern "C" void kernel_launch(void* const* d_in, const int* in_sizes, int n_in,
                              void* d_out, int out_size, void* d_ws, size_t ws_size,
                              hipStream_t stream) {
  const float* x    = (const float*)d_in[0];
  const float* W1   = (const float*)d_in[1];
  const float* b1   = (const float*)d_in[2];
  const float* W2   = (const float*)d_in[3];
  const float* b2   = (const float*)d_in[4];
  const float* Wp   = (const float*)d_in[5];
  const float* bp   = (const float*)d_in[6];
  const int*   ei   = (const int*)d_in[7];
  const int*   batch= (const int*)d_in[8];
  float* out = (float*)d_out;

  const int N = N_NODES, E = N_EDGESC;
  const int* src  = ei;        // edge_index[0]
  const int* dstp = ei + E;    // edge_index[1]

  char* wsb = (char*)d_ws;
  size_t o = 0;
  auto alloc = [&](size_t bytes) -> void* {
    void* p = wsb + o;
    o = (o + bytes + 255) & ~(size_t)255;
    return p;
  };
  int*      gcur   = (int*)alloc(NBUCK * 4);
  int*      boff   = (int*)alloc(NBUCK * 4);
  unsigned* bbuf   = (unsigned*)alloc((size_t)NBUCK * BCAP * 4);
  int*      row_off= (int*)alloc((size_t)(N + 1) * 4);
  int*      csr    = (int*)alloc((size_t)E * 4);
  float*    dinv   = (float*)alloc((size_t)N * 4);
  unsigned short* bufBF = (unsigned short*)alloc((size_t)N * 64 * 2);
  float*    bufF   = (float*)alloc((size_t)N * 64 * 4);
  float*    gmean  = (float*)alloc(64 * 64 * 4);

  hipMemsetAsync(gcur, 0, NBUCK * 4, stream);

  int gA = (E + CHUNK - 1) / CHUNK;   // 196
  int gN64 = (N + 63) / 64;           // 782

  k_bucket<<<gA, 256, 0, stream>>>(src, dstp, gcur, bbuf, E);
  k_bscan<<<1, 256, 0, stream>>>(gcur, boff);
  k_bsort<<<NBUCK, 256, 0, stream>>>(bbuf, gcur, boff, csr, row_off, dinv, E);

  k_gemm<128><<<gN64, 64, 0, stream>>>(x, W1, dinv, bufBF, N);
  k_gather<<<2048, 256, 0, stream>>>(bufBF, row_off, csr, dinv, b1, bufF, N);
  k_gemm<64><<<gN64, 64, 0, stream>>>(bufF, W2, dinv, bufBF, N);
  k_gather<<<2048, 256, 0, stream>>>(bufBF, row_off, csr, dinv, b2, bufF, N);

  k_pool<<<N_GRAPHS, 256, 0, stream>>>(bufF, batch, gmean, N);
  k_final<<<16, 256, 0, stream>>>(gmean, Wp, bp, out);
}

// Round 4
// 278.257 us; speedup vs baseline: 2.0208x; 1.4411x over previous
//
#include <hip/hip_runtime.h>

#define N_NODES  50000
#define N_EDGESC 1600000
#define N_GRAPHS 64
#define NBUCK    196      // ceil(50000/256) buckets of 256 dst nodes
#define BCAP     10240    // >> E/NBUCK (8163) + 20 sigma
#define CHUNK    8192     // edges per bucketing block

static __device__ __forceinline__ unsigned short f2bf(float f) {
  unsigned u = __float_as_uint(f);
  u += 0x7FFF + ((u >> 16) & 1);          // RNE
  return (unsigned short)(u >> 16);
}
static __device__ __forceinline__ float bf2f(unsigned short u) {
  return __uint_as_float(((unsigned)u) << 16);
}

static __device__ __forceinline__ int lowerb(const int* a, int n, int v) {
  int lo = 0, hi = n;
  while (lo < hi) { int m = (lo + hi) >> 1; if (a[m] < v) lo = m + 1; else hi = m; }
  return lo;
}

// Phase A: chunk-bucket edges by dst>>8; per-(block,bucket) runs are
// sequential -> mostly full-line writes. Entry packed (local_dst<<24)|src.
__global__ __launch_bounds__(256) void k_bucket(const int* __restrict__ src,
                                                const int* __restrict__ dst,
                                                int* __restrict__ gcur,
                                                unsigned* __restrict__ bbuf, int E) {
  __shared__ int hist[NBUCK], base[NBUCK], cur[NBUCK];
  int t = threadIdx.x;
  if (t < NBUCK) { hist[t] = 0; cur[t] = 0; }
  __syncthreads();
  int e0 = blockIdx.x * CHUNK;
  for (int i = 0; i < CHUNK; i += 256) {
    int e = e0 + i + t;
    if (e < E) atomicAdd(&hist[dst[e] >> 8], 1);
  }
  __syncthreads();
  if (t < NBUCK) base[t] = hist[t] ? atomicAdd(&gcur[t], hist[t]) : 0;
  __syncthreads();
  for (int i = 0; i < CHUNK; i += 256) {
    int e = e0 + i + t;
    if (e < E) {
      int d = dst[e], b = d >> 8;
      int pos = base[b] + atomicAdd(&cur[b], 1);
      unsigned packed = ((unsigned)(d & 255) << 24) | (unsigned)src[e];
      if (pos < BCAP) bbuf[(size_t)b * BCAP + pos] = packed;
    }
  }
}

// exclusive scan of the 196 bucket totals
__global__ void k_bscan(const int* __restrict__ gcur, int* __restrict__ boff) {
  __shared__ int sm[256];
  int t = threadIdx.x;
  int v = (t < NBUCK) ? gcur[t] : 0;
  sm[t] = v;
  __syncthreads();
  for (int o = 1; o < 256; o <<= 1) {
    int add = (t >= o) ? sm[t - o] : 0;
    __syncthreads();
    sm[t] += add;
    __syncthreads();
  }
  if (t < NBUCK) boff[t] = sm[t] - v;
}

// Phase B: per-bucket counting sort -> csr segment + row_off + dinv.
__global__ __launch_bounds__(256) void k_bsort(const unsigned* __restrict__ bbuf,
                                               const int* __restrict__ gcur,
                                               const int* __restrict__ boff,
                                               int* __restrict__ csr,
                                               int* __restrict__ row_off,
                                               float* __restrict__ dinv, int E) {
  __shared__ int hist[256], off[256], cur[256];
  int b = blockIdx.x, t = threadIdx.x;
  hist[t] = 0; cur[t] = 0;
  __syncthreads();
  int cnt = min(gcur[b], BCAP);
  const unsigned* bp = bbuf + (size_t)b * BCAP;
  for (int i = t; i < cnt; i += 256) atomicAdd(&hist[bp[i] >> 24], 1);
  __syncthreads();
  off[t] = hist[t];
  __syncthreads();
  for (int o = 1; o < 256; o <<= 1) {
    int add = (t >= o) ? off[t - o] : 0;
    __syncthreads();
    off[t] += add;
    __syncthreads();
  }
  int excl = off[t] - hist[t];
  __syncthreads();
  off[t] = excl;
  __syncthreads();
  int gb = boff[b];
  int idx = (b << 8) + t;
  if (idx <= N_NODES) row_off[idx] = gb + off[t];
  if (idx < N_NODES)  dinv[idx] = rsqrtf((float)(hist[t] + 1));  // +1 self-loop
  for (int i = t; i < cnt; i += 256) {
    unsigned v = bp[i];
    int ld = v >> 24;
    int pos = atomicAdd(&cur[ld], 1);
    csr[gb + off[ld] + pos] = (int)(v & 0xFFFFFFu);
  }
}

// out_bf16[i][c] = bf16( (x[i,:] @ W[:,c]) * dinv[i] )
// lane = node; x AND W staged in LDS. W reads are wave-uniform ds_read_b128
// broadcasts (no scalar-cache thrash); xs padded K+1 -> conflict-free b32.
template <int K>
__global__ __launch_bounds__(64) void k_gemm(const float* __restrict__ x,
                                             const float* __restrict__ W,
                                             const float* __restrict__ dinv,
                                             unsigned short* __restrict__ out, int N) {
  constexpr int KP = K + 1;
  __shared__ float xs[64 * KP];   // K=128: 33KB ; K=64: 16.6KB
  __shared__ float Wl[K * 64];    // K=128: 32KB ; K=64: 16KB
  const int lane = threadIdx.x;
  const int n0 = blockIdx.x * 64;

  // stage W (K*16 float4s, 64 lanes)
#pragma unroll 4
  for (int it = 0; it < K / 4; ++it) {
    int li = it * 64 + lane;
    float4 w = *reinterpret_cast<const float4*>(W + li * 4);
    float* dp = Wl + li * 4;
    dp[0] = w.x; dp[1] = w.y; dp[2] = w.z; dp[3] = w.w;
  }

  // stage x tile, coalesced float4 loads
  constexpr int NF4 = K / 4;
  constexpr int ITERS = 64 * NF4 / 64;
#pragma unroll 4
  for (int it = 0; it < ITERS; ++it) {
    int li = it * 64 + lane;
    int row = li / NF4;
    int c4 = li % NF4;
    int node = n0 + row;
    float4 v = make_float4(0.f, 0.f, 0.f, 0.f);
    if (node < N) v = *reinterpret_cast<const float4*>(x + (size_t)node * K + c4 * 4);
    float* dp = xs + row * KP + c4 * 4;
    dp[0] = v.x; dp[1] = v.y; dp[2] = v.z; dp[3] = v.w;
  }
  __syncthreads();

  float acc[64];
#pragma unroll
  for (int c = 0; c < 64; ++c) acc[c] = 0.f;

  const float* xr = xs + lane * KP;
#pragma unroll 2
  for (int k = 0; k < K; ++k) {
    float xv = xr[k];                                           // conflict-free
    const float4* wr = reinterpret_cast<const float4*>(Wl + k * 64);  // uniform -> broadcast
#pragma unroll
    for (int j = 0; j < 16; ++j) {
      float4 w = wr[j];
      acc[4 * j + 0] = fmaf(xv, w.x, acc[4 * j + 0]);
      acc[4 * j + 1] = fmaf(xv, w.y, acc[4 * j + 1]);
      acc[4 * j + 2] = fmaf(xv, w.z, acc[4 * j + 2]);
      acc[4 * j + 3] = fmaf(xv, w.w, acc[4 * j + 3]);
    }
  }

  int node = n0 + lane;
  float dv = (node < N) ? dinv[node] : 0.f;

  // transpose through LDS for coalesced bf16 stores (reuse xs; 64*65 <= 64*KP)
  __syncthreads();
#pragma unroll
  for (int c = 0; c < 64; ++c) xs[lane * 65 + c] = acc[c] * dv;
  __syncthreads();
#pragma unroll
  for (int it = 0; it < 16; ++it) {
    int f4 = it * 64 + lane;
    int nd = f4 >> 4;
    int c4 = f4 & 15;
    if (n0 + nd < N) {
      const float* sp = xs + nd * 65 + c4 * 4;
      ushort4 u;
      u.x = f2bf(sp[0]); u.y = f2bf(sp[1]); u.z = f2bf(sp[2]); u.w = f2bf(sp[3]);
      *reinterpret_cast<ushort4*>(out + (size_t)(n0 + nd) * 64 + c4 * 4) = u;
    }
  }
}

// out[i][c] = relu( dinv[i]*(hs[i][c] + sum_{s} hs[s][c]) + bias[c] ), hs bf16.
// 16-deep batched gather: 16 uniform csr reads (L1 broadcast) + 16 independent
// row loads (32-bit SADDR offsets) before any add -> MLP 16/wave.
__global__ __launch_bounds__(256) void k_gather(const unsigned short* __restrict__ hs,
                                                const int* __restrict__ row_off,
                                                const int* __restrict__ csr,
                                                const float* __restrict__ dinv,
                                                const float* __restrict__ bias,
                                                float* __restrict__ out, int N) {
  const int c = threadIdx.x & 63;
  int wid = blockIdx.x * 4 + (threadIdx.x >> 6);
  int stride = gridDim.x * 4;
  float bc = bias[c];
  for (int i = wid; i < N; i += stride) {
    float acc = bf2f(hs[(((unsigned)i) << 6) + c]);   // self-loop term
    const int s0 = row_off[i], s1 = row_off[i + 1];
    int j = s0;
    for (; j + 16 <= s1; j += 16) {
      int idx[16];
#pragma unroll
      for (int q = 0; q < 16; ++q) idx[q] = csr[j + q];          // uniform, L1
      float v[16];
#pragma unroll
      for (int q = 0; q < 16; ++q)
        v[q] = bf2f(hs[(((unsigned)idx[q]) << 6) + c]);          // 16 in flight
#pragma unroll
      for (int q = 0; q < 16; ++q) acc += v[q];
    }
    if (j < s1) {                                                // clamped tail
      int idx[16];
#pragma unroll
      for (int q = 0; q < 16; ++q) idx[q] = csr[min(j + q, s1 - 1)];
      float v[16];
#pragma unroll
      for (int q = 0; q < 16; ++q)
        v[q] = bf2f(hs[(((unsigned)idx[q]) << 6) + c]);
#pragma unroll
      for (int q = 0; q < 16; ++q) acc += (j + q < s1) ? v[q] : 0.f;
    }
    out[(((unsigned)i) << 6) + c] = fmaxf(fmaf(acc, dinv[i], bc), 0.0f);
  }
}

__global__ void k_pool(const float* __restrict__ h, const int* __restrict__ batch,
                       float* __restrict__ gmean, int N) {
  int g = blockIdx.x;
  int lo = lowerb(batch, N, g);
  int hi = lowerb(batch, N, g + 1);
  int w = threadIdx.x >> 6, c = threadIdx.x & 63;
  float acc = 0.f;
  for (int i = lo + w; i < hi; i += 4) acc += h[(size_t)i * 64 + c];
  __shared__ float sm[4][64];
  sm[w][c] = acc;
  __syncthreads();
  if (w == 0) {
    float s = sm[0][c] + sm[1][c] + sm[2][c] + sm[3][c];
    float n = (float)(hi - lo);
    gmean[g * 64 + c] = s / fmaxf(n, 1.0f);
  }
}

__global__ void k_final(const float* __restrict__ gmean, const float* __restrict__ Wp,
                        const float* __restrict__ bp, float* __restrict__ out) {
  int idx = blockIdx.x * 256 + threadIdx.x;
  int g = idx >> 6, o = idx & 63;
  float acc = bp[o];
#pragma unroll
  for (int k = 0; k < 64; ++k) acc += gmean[g * 64 + k] * Wp[k * 64 + o];
  out[idx] = acc;
}

extern "C" void kernel_launch(void* const* d_in, const int* in_sizes, int n_in,
                              void* d_out, int out_size, void* d_ws, size_t ws_size,
                              hipStream_t stream) {
  const float* x    = (const float*)d_in[0];
  const float* W1   = (const float*)d_in[1];
  const float* b1   = (const float*)d_in[2];
  const float* W2   = (const float*)d_in[3];
  const float* b2   = (const float*)d_in[4];
  const float* Wp   = (const float*)d_in[5];
  const float* bp   = (const float*)d_in[6];
  const int*   ei   = (const int*)d_in[7];
  const int*   batch= (const int*)d_in[8];
  float* out = (float*)d_out;

  const int N = N_NODES, E = N_EDGESC;
  const int* src  = ei;        // edge_index[0]
  const int* dstp = ei + E;    // edge_index[1]

  char* wsb = (char*)d_ws;
  size_t o = 0;
  auto alloc = [&](size_t bytes) -> void* {
    void* p = wsb + o;
    o = (o + bytes + 255) & ~(size_t)255;
    return p;
  };
  int*      gcur   = (int*)alloc(NBUCK * 4);
  int*      boff   = (int*)alloc(NBUCK * 4);
  unsigned* bbuf   = (unsigned*)alloc((size_t)NBUCK * BCAP * 4);
  int*      row_off= (int*)alloc((size_t)(N + 1) * 4);
  int*      csr    = (int*)alloc((size_t)E * 4);
  float*    dinv   = (float*)alloc((size_t)N * 4);
  unsigned short* bufBF = (unsigned short*)alloc((size_t)N * 64 * 2);
  float*    bufF   = (float*)alloc((size_t)N * 64 * 4);
  float*    gmean  = (float*)alloc(64 * 64 * 4);

  hipMemsetAsync(gcur, 0, NBUCK * 4, stream);

  int gA = (E + CHUNK - 1) / CHUNK;   // 196
  int gN64 = (N + 63) / 64;           // 782

  k_bucket<<<gA, 256, 0, stream>>>(src, dstp, gcur, bbuf, E);
  k_bscan<<<1, 256, 0, stream>>>(gcur, boff);
  k_bsort<<<NBUCK, 256, 0, stream>>>(bbuf, gcur, boff, csr, row_off, dinv, E);

  k_gemm<128><<<gN64, 64, 0, stream>>>(x, W1, dinv, bufBF, N);
  k_gather<<<2048, 256, 0, stream>>>(bufBF, row_off, csr, dinv, b1, bufF, N);
  k_gemm<64><<<gN64, 64, 0, stream>>>(bufF, W2, dinv, bufBF, N);
  k_gather<<<2048, 256, 0, stream>>>(bufBF, row_off, csr, dinv, b2, bufF, N);

  k_pool<<<N_GRAPHS, 256, 0, stream>>>(bufF, batch, gmean, N);
  k_final<<<16, 256, 0, stream>>>(gmean, Wp, bp, out);
}

// Round 5
// 261.561 us; speedup vs baseline: 2.1498x; 1.0638x over previous
//
#include <hip/hip_runtime.h>

#define N_NODES  50000
#define N_EDGESC 1600000
#define N_GRAPHS 64
#define NBUCK    196      // ceil(50000/256) buckets of 256 dst nodes
#define BCAP     10240    // >> E/NBUCK (8163) + 20 sigma
#define CHUNK    8192     // edges per bucketing block

static __device__ __forceinline__ unsigned short f2bf(float f) {
  unsigned u = __float_as_uint(f);
  u += 0x7FFF + ((u >> 16) & 1);          // RNE
  return (unsigned short)(u >> 16);
}
static __device__ __forceinline__ float bf2f(unsigned short u) {
  return __uint_as_float(((unsigned)u) << 16);
}

static __device__ __forceinline__ int lowerb(const int* a, int n, int v) {
  int lo = 0, hi = n;
  while (lo < hi) { int m = (lo + hi) >> 1; if (a[m] < v) lo = m + 1; else hi = m; }
  return lo;
}

// Phase A: chunk-bucket edges by dst>>8; per-(block,bucket) runs are
// sequential -> mostly full-line writes. Entry packed (local_dst<<24)|src.
__global__ __launch_bounds__(256) void k_bucket(const int* __restrict__ src,
                                                const int* __restrict__ dst,
                                                int* __restrict__ gcur,
                                                unsigned* __restrict__ bbuf, int E) {
  __shared__ int hist[NBUCK], base[NBUCK], cur[NBUCK];
  int t = threadIdx.x;
  if (t < NBUCK) { hist[t] = 0; cur[t] = 0; }
  __syncthreads();
  int e0 = blockIdx.x * CHUNK;
  for (int i = 0; i < CHUNK; i += 256) {
    int e = e0 + i + t;
    if (e < E) atomicAdd(&hist[dst[e] >> 8], 1);
  }
  __syncthreads();
  if (t < NBUCK) base[t] = hist[t] ? atomicAdd(&gcur[t], hist[t]) : 0;
  __syncthreads();
  for (int i = 0; i < CHUNK; i += 256) {
    int e = e0 + i + t;
    if (e < E) {
      int d = dst[e], b = d >> 8;
      int pos = base[b] + atomicAdd(&cur[b], 1);
      unsigned packed = ((unsigned)(d & 255) << 24) | (unsigned)src[e];
      if (pos < BCAP) bbuf[(size_t)b * BCAP + pos] = packed;
    }
  }
}

// exclusive scan of the 196 bucket totals
__global__ void k_bscan(const int* __restrict__ gcur, int* __restrict__ boff) {
  __shared__ int sm[256];
  int t = threadIdx.x;
  int v = (t < NBUCK) ? gcur[t] : 0;
  sm[t] = v;
  __syncthreads();
  for (int o = 1; o < 256; o <<= 1) {
    int add = (t >= o) ? sm[t - o] : 0;
    __syncthreads();
    sm[t] += add;
    __syncthreads();
  }
  if (t < NBUCK) boff[t] = sm[t] - v;
}

// Phase B: per-bucket counting sort -> csr segment + row_off + dinv.
__global__ __launch_bounds__(256) void k_bsort(const unsigned* __restrict__ bbuf,
                                               const int* __restrict__ gcur,
                                               const int* __restrict__ boff,
                                               int* __restrict__ csr,
                                               int* __restrict__ row_off,
                                               float* __restrict__ dinv, int E) {
  __shared__ int hist[256], off[256], cur[256];
  int b = blockIdx.x, t = threadIdx.x;
  hist[t] = 0; cur[t] = 0;
  __syncthreads();
  int cnt = min(gcur[b], BCAP);
  const unsigned* bp = bbuf + (size_t)b * BCAP;
  for (int i = t; i < cnt; i += 256) atomicAdd(&hist[bp[i] >> 24], 1);
  __syncthreads();
  off[t] = hist[t];
  __syncthreads();
  for (int o = 1; o < 256; o <<= 1) {
    int add = (t >= o) ? off[t - o] : 0;
    __syncthreads();
    off[t] += add;
    __syncthreads();
  }
  int excl = off[t] - hist[t];
  __syncthreads();
  off[t] = excl;
  __syncthreads();
  int gb = boff[b];
  int idx = (b << 8) + t;
  if (idx <= N_NODES) row_off[idx] = gb + off[t];
  if (idx < N_NODES)  dinv[idx] = rsqrtf((float)(hist[t] + 1));  // +1 self-loop
  for (int i = t; i < cnt; i += 256) {
    unsigned v = bp[i];
    int ld = v >> 24;
    int pos = atomicAdd(&cur[ld], 1);
    csr[gb + off[ld] + pos] = (int)(v & 0xFFFFFFu);
  }
}

// out_bf16[i][c] = bf16( (x[i,:] @ W[:,c]) * dinv[i] )
// Block = 256 thr = 4 waves sharing one 64-node xs tile + full W in LDS.
// Wave w -> channels [16w,16w+16): lane = node, acc[16].
// Per 4-k packet: 1 per-lane ds_read_b128 (xs, K+4 pad) + 16 wave-uniform
// b128 W broadcasts + 64 FMA -> VALU-bound; 2 blocks/CU = 8 waves/CU.
template <int K>
__global__ __launch_bounds__(256) void k_gemm(const float* __restrict__ x,
                                              const float* __restrict__ W,
                                              const float* __restrict__ dinv,
                                              unsigned short* __restrict__ out, int N) {
  constexpr int KP = K + 4;
  __shared__ float xs[64 * KP];   // K=128: 33.8KB ; K=64: 17.4KB
  __shared__ float Wl[K * 64];    // K=128: 32KB   ; K=64: 16KB
  const int t = threadIdx.x;
  const int lane = t & 63;
  const int w = t >> 6;
  const int n0 = blockIdx.x * 64;

  // stage W (row-major [k][64]); consecutive threads -> consecutive float4
#pragma unroll
  for (int i = 0; i < K * 16 / 256; ++i) {
    int li = i * 256 + t;
    float4 v = reinterpret_cast<const float4*>(W)[li];
    *reinterpret_cast<float4*>(Wl + li * 4) = v;
  }
  // stage x tile (64 rows x K), coalesced
  constexpr int NF4 = K / 4;
#pragma unroll
  for (int i = 0; i < 64 * NF4 / 256; ++i) {
    int li = i * 256 + t;
    int row = li / NF4, c4 = li % NF4;
    int node = n0 + row;
    float4 v = make_float4(0.f, 0.f, 0.f, 0.f);
    if (node < N) v = reinterpret_cast<const float4*>(x + (size_t)node * K)[c4];
    *reinterpret_cast<float4*>(xs + row * KP + c4 * 4) = v;
  }
  __syncthreads();

  float acc[16];
#pragma unroll
  for (int j = 0; j < 16; ++j) acc[j] = 0.f;

  const float* xr = xs + lane * KP;
  const float* wq = Wl + w * 16;
#pragma unroll 8
  for (int kp = 0; kp < K / 4; ++kp) {
    float4 xv = *reinterpret_cast<const float4*>(xr + kp * 4);
#pragma unroll
    for (int q = 0; q < 4; ++q) {
      int k = kp * 4 + q;
      float xq = (q == 0) ? xv.x : (q == 1) ? xv.y : (q == 2) ? xv.z : xv.w;
      const float* wk = wq + k * 64;                 // wave-uniform address
      float4 w0 = *reinterpret_cast<const float4*>(wk);
      float4 w1 = *reinterpret_cast<const float4*>(wk + 4);
      float4 w2 = *reinterpret_cast<const float4*>(wk + 8);
      float4 w3 = *reinterpret_cast<const float4*>(wk + 12);
      acc[ 0] = fmaf(xq, w0.x, acc[ 0]);
      acc[ 1] = fmaf(xq, w0.y, acc[ 1]);
      acc[ 2] = fmaf(xq, w0.z, acc[ 2]);
      acc[ 3] = fmaf(xq, w0.w, acc[ 3]);
      acc[ 4] = fmaf(xq, w1.x, acc[ 4]);
      acc[ 5] = fmaf(xq, w1.y, acc[ 5]);
      acc[ 6] = fmaf(xq, w1.z, acc[ 6]);
      acc[ 7] = fmaf(xq, w1.w, acc[ 7]);
      acc[ 8] = fmaf(xq, w2.x, acc[ 8]);
      acc[ 9] = fmaf(xq, w2.y, acc[ 9]);
      acc[10] = fmaf(xq, w2.z, acc[10]);
      acc[11] = fmaf(xq, w2.w, acc[11]);
      acc[12] = fmaf(xq, w3.x, acc[12]);
      acc[13] = fmaf(xq, w3.y, acc[13]);
      acc[14] = fmaf(xq, w3.z, acc[14]);
      acc[15] = fmaf(xq, w3.w, acc[15]);
    }
  }

  int node = n0 + lane;
  if (node < N) {
    float dv = dinv[node];
    unsigned pk[8];
#pragma unroll
    for (int j = 0; j < 8; ++j) {
      unsigned lo = f2bf(acc[2 * j] * dv);
      unsigned hi = f2bf(acc[2 * j + 1] * dv);
      pk[j] = lo | (hi << 16);
    }
    unsigned* op = reinterpret_cast<unsigned*>(out + (size_t)node * 64 + w * 16);
    *reinterpret_cast<uint4*>(op)     = make_uint4(pk[0], pk[1], pk[2], pk[3]);
    *reinterpret_cast<uint4*>(op + 4) = make_uint4(pk[4], pk[5], pk[6], pk[7]);
  }
}

// out[i][c] = relu( dinv[i]*(hs[i][c] + sum_{s} hs[s][c]) + bias[c] ), hs bf16.
// 16-deep batched gather: 16 uniform csr reads (L1 broadcast) + 16 independent
// row loads before any add -> MLP 16/wave.
__global__ __launch_bounds__(256) void k_gather(const unsigned short* __restrict__ hs,
                                                const int* __restrict__ row_off,
                                                const int* __restrict__ csr,
                                                const float* __restrict__ dinv,
                                                const float* __restrict__ bias,
                                                float* __restrict__ out, int N) {
  const int c = threadIdx.x & 63;
  int wid = blockIdx.x * 4 + (threadIdx.x >> 6);
  int stride = gridDim.x * 4;
  float bc = bias[c];
  for (int i = wid; i < N; i += stride) {
    float acc = bf2f(hs[(((unsigned)i) << 6) + c]);   // self-loop term
    const int s0 = row_off[i], s1 = row_off[i + 1];
    int j = s0;
    for (; j + 16 <= s1; j += 16) {
      int idx[16];
#pragma unroll
      for (int q = 0; q < 16; ++q) idx[q] = csr[j + q];          // uniform, L1
      float v[16];
#pragma unroll
      for (int q = 0; q < 16; ++q)
        v[q] = bf2f(hs[(((unsigned)idx[q]) << 6) + c]);          // 16 in flight
#pragma unroll
      for (int q = 0; q < 16; ++q) acc += v[q];
    }
    if (j < s1) {                                                // clamped tail
      int idx[16];
#pragma unroll
      for (int q = 0; q < 16; ++q) idx[q] = csr[min(j + q, s1 - 1)];
      float v[16];
#pragma unroll
      for (int q = 0; q < 16; ++q)
        v[q] = bf2f(hs[(((unsigned)idx[q]) << 6) + c]);
#pragma unroll
      for (int q = 0; q < 16; ++q) acc += (j + q < s1) ? v[q] : 0.f;
    }
    out[(((unsigned)i) << 6) + c] = fmaxf(fmaf(acc, dinv[i], bc), 0.0f);
  }
}

__global__ void k_pool(const float* __restrict__ h, const int* __restrict__ batch,
                       float* __restrict__ gmean, int N) {
  int g = blockIdx.x;
  int lo = lowerb(batch, N, g);
  int hi = lowerb(batch, N, g + 1);
  int w = threadIdx.x >> 6, c = threadIdx.x & 63;
  float acc = 0.f;
  for (int i = lo + w; i < hi; i += 4) acc += h[(size_t)i * 64 + c];
  __shared__ float sm[4][64];
  sm[w][c] = acc;
  __syncthreads();
  if (w == 0) {
    float s = sm[0][c] + sm[1][c] + sm[2][c] + sm[3][c];
    float n = (float)(hi - lo);
    gmean[g * 64 + c] = s / fmaxf(n, 1.0f);
  }
}

__global__ void k_final(const float* __restrict__ gmean, const float* __restrict__ Wp,
                        const float* __restrict__ bp, float* __restrict__ out) {
  int idx = blockIdx.x * 256 + threadIdx.x;
  int g = idx >> 6, o = idx & 63;
  float acc = bp[o];
#pragma unroll
  for (int k = 0; k < 64; ++k) acc += gmean[g * 64 + k] * Wp[k * 64 + o];
  out[idx] = acc;
}

extern "C" void kernel_launch(void* const* d_in, const int* in_sizes, int n_in,
                              void* d_out, int out_size, void* d_ws, size_t ws_size,
                              hipStream_t stream) {
  const float* x    = (const float*)d_in[0];
  const float* W1   = (const float*)d_in[1];
  const float* b1   = (const float*)d_in[2];
  const float* W2   = (const float*)d_in[3];
  const float* b2   = (const float*)d_in[4];
  const float* Wp   = (const float*)d_in[5];
  const float* bp   = (const float*)d_in[6];
  const int*   ei   = (const int*)d_in[7];
  const int*   batch= (const int*)d_in[8];
  float* out = (float*)d_out;

  const int N = N_NODES, E = N_EDGESC;
  const int* src  = ei;        // edge_index[0]
  const int* dstp = ei + E;    // edge_index[1]

  char* wsb = (char*)d_ws;
  size_t o = 0;
  auto alloc = [&](size_t bytes) -> void* {
    void* p = wsb + o;
    o = (o + bytes + 255) & ~(size_t)255;
    return p;
  };
  int*      gcur   = (int*)alloc(NBUCK * 4);
  int*      boff   = (int*)alloc(NBUCK * 4);
  unsigned* bbuf   = (unsigned*)alloc((size_t)NBUCK * BCAP * 4);
  int*      row_off= (int*)alloc((size_t)(N + 1) * 4);
  int*      csr    = (int*)alloc((size_t)E * 4);
  float*    dinv   = (float*)alloc((size_t)N * 4);
  unsigned short* bufBF = (unsigned short*)alloc((size_t)N * 64 * 2);
  float*    bufF   = (float*)alloc((size_t)N * 64 * 4);
  float*    gmean  = (float*)alloc(64 * 64 * 4);

  hipMemsetAsync(gcur, 0, NBUCK * 4, stream);

  int gA = (E + CHUNK - 1) / CHUNK;   // 196
  int gN64 = (N + 63) / 64;           // 782

  k_bucket<<<gA, 256, 0, stream>>>(src, dstp, gcur, bbuf, E);
  k_bscan<<<1, 256, 0, stream>>>(gcur, boff);
  k_bsort<<<NBUCK, 256, 0, stream>>>(bbuf, gcur, boff, csr, row_off, dinv, E);

  k_gemm<128><<<gN64, 256, 0, stream>>>(x, W1, dinv, bufBF, N);
  k_gather<<<2048, 256, 0, stream>>>(bufBF, row_off, csr, dinv, b1, bufF, N);
  k_gemm<64><<<gN64, 256, 0, stream>>>(bufF, W2, dinv, bufBF, N);
  k_gather<<<2048, 256, 0, stream>>>(bufBF, row_off, csr, dinv, b2, bufF, N);

  k_pool<<<N_GRAPHS, 256, 0, stream>>>(bufF, batch, gmean, N);
  k_final<<<16, 256, 0, stream>>>(gmean, Wp, bp, out);
}

// Round 6
// 207.398 us; speedup vs baseline: 2.7113x; 1.2612x over previous
//
#include <hip/hip_runtime.h>

#define N_NODES  50000
#define N_EDGESC 1600000
#define N_GRAPHS 64
#define NBUCK    196      // ceil(50000/256) buckets of 256 dst nodes
#define BCAP     10240    // >> E/NBUCK (8163) + 20 sigma
#define CHUNK    8192     // edges per bucketing block

static __device__ __forceinline__ unsigned short f2bf(float f) {
  unsigned u = __float_as_uint(f);
  u += 0x7FFF + ((u >> 16) & 1);          // RNE
  return (unsigned short)(u >> 16);
}
static __device__ __forceinline__ float bf2f(unsigned short u) {
  return __uint_as_float(((unsigned)u) << 16);
}

static __device__ __forceinline__ int lowerb(const int* a, int n, int v) {
  int lo = 0, hi = n;
  while (lo < hi) { int m = (lo + hi) >> 1; if (a[m] < v) lo = m + 1; else hi = m; }
  return lo;
}

// Phase A: chunk-bucket edges by dst>>8; per-(block,bucket) runs are
// sequential -> mostly full-line writes. Entry packed (local_dst<<24)|src.
__global__ __launch_bounds__(256) void k_bucket(const int* __restrict__ src,
                                                const int* __restrict__ dst,
                                                int* __restrict__ gcur,
                                                unsigned* __restrict__ bbuf, int E) {
  __shared__ int hist[NBUCK], base[NBUCK], cur[NBUCK];
  int t = threadIdx.x;
  if (t < NBUCK) { hist[t] = 0; cur[t] = 0; }
  __syncthreads();
  int e0 = blockIdx.x * CHUNK;
  for (int i = 0; i < CHUNK; i += 256) {
    int e = e0 + i + t;
    if (e < E) atomicAdd(&hist[dst[e] >> 8], 1);
  }
  __syncthreads();
  if (t < NBUCK) base[t] = hist[t] ? atomicAdd(&gcur[t], hist[t]) : 0;
  __syncthreads();
  for (int i = 0; i < CHUNK; i += 256) {
    int e = e0 + i + t;
    if (e < E) {
      int d = dst[e], b = d >> 8;
      int pos = base[b] + atomicAdd(&cur[b], 1);
      unsigned packed = ((unsigned)(d & 255) << 24) | (unsigned)src[e];
      if (pos < BCAP) bbuf[(size_t)b * BCAP + pos] = packed;
    }
  }
}

// exclusive scan of the 196 bucket totals
__global__ void k_bscan(const int* __restrict__ gcur, int* __restrict__ boff) {
  __shared__ int sm[256];
  int t = threadIdx.x;
  int v = (t < NBUCK) ? gcur[t] : 0;
  sm[t] = v;
  __syncthreads();
  for (int o = 1; o < 256; o <<= 1) {
    int add = (t >= o) ? sm[t - o] : 0;
    __syncthreads();
    sm[t] += add;
    __syncthreads();
  }
  if (t < NBUCK) boff[t] = sm[t] - v;
}

// Phase B: per-bucket counting sort -> csr segment + row_off + dinv.
__global__ __launch_bounds__(256) void k_bsort(const unsigned* __restrict__ bbuf,
                                               const int* __restrict__ gcur,
                                               const int* __restrict__ boff,
                                               int* __restrict__ csr,
                                               int* __restrict__ row_off,
                                               float* __restrict__ dinv, int E) {
  __shared__ int hist[256], off[256], cur[256];
  int b = blockIdx.x, t = threadIdx.x;
  hist[t] = 0; cur[t] = 0;
  __syncthreads();
  int cnt = min(gcur[b], BCAP);
  const unsigned* bp = bbuf + (size_t)b * BCAP;
  for (int i = t; i < cnt; i += 256) atomicAdd(&hist[bp[i] >> 24], 1);
  __syncthreads();
  off[t] = hist[t];
  __syncthreads();
  for (int o = 1; o < 256; o <<= 1) {
    int add = (t >= o) ? off[t - o] : 0;
    __syncthreads();
    off[t] += add;
    __syncthreads();
  }
  int excl = off[t] - hist[t];
  __syncthreads();
  off[t] = excl;
  __syncthreads();
  int gb = boff[b];
  int idx = (b << 8) + t;
  if (idx <= N_NODES) row_off[idx] = gb + off[t];
  if (idx < N_NODES)  dinv[idx] = rsqrtf((float)(hist[t] + 1));  // +1 self-loop
  for (int i = t; i < cnt; i += 256) {
    unsigned v = bp[i];
    int ld = v >> 24;
    int pos = atomicAdd(&cur[ld], 1);
    csr[gb + off[ld] + pos] = (int)(v & 0xFFFFFFu);
  }
}

// out_bf16[i][c] = bf16( (x[i,:] @ W[:,c]) * dinv[i] )
// Block = 256 thr = 4 waves; K-step=64 blocking: xs 64x68 (17.4KB) + W-slice
// 64x64 (16KB) = ~34KB LDS -> 4 blocks/CU = 16 waves/CU. Wave w -> channels
// [16w,16w+16): lane = node, acc[16]. W reads wave-uniform b128 broadcasts.
template <int K>
__global__ __launch_bounds__(256) void k_gemm(const float* __restrict__ x,
                                              const float* __restrict__ W,
                                              const float* __restrict__ dinv,
                                              unsigned short* __restrict__ out, int N) {
  constexpr int KS = 64;            // K-step
  constexpr int KP = KS + 4;        // padded xs row stride
  __shared__ float xs[64 * KP];     // 17.4 KB
  __shared__ float Wl[KS * 64];     // 16 KB
  const int t = threadIdx.x;
  const int lane = t & 63;
  const int w = t >> 6;
  const int n0 = blockIdx.x * 64;

  float acc[16];
#pragma unroll
  for (int j = 0; j < 16; ++j) acc[j] = 0.f;

  for (int h = 0; h < K / KS; ++h) {
    // stage W rows [h*KS, h*KS+KS): KS*16 float4 over 256 threads
#pragma unroll
    for (int i = 0; i < KS * 16 / 256; ++i) {
      int li = i * 256 + t;
      float4 v = reinterpret_cast<const float4*>(W + h * KS * 64)[li];
      *reinterpret_cast<float4*>(Wl + li * 4) = v;
    }
    // stage xs: 64 rows x KS cols
#pragma unroll
    for (int i = 0; i < 64 * (KS / 4) / 256; ++i) {
      int li = i * 256 + t;
      int row = li / (KS / 4), c4 = li % (KS / 4);
      int node = n0 + row;
      float4 v = make_float4(0.f, 0.f, 0.f, 0.f);
      if (node < N) v = reinterpret_cast<const float4*>(x + (size_t)node * K + h * KS)[c4];
      *reinterpret_cast<float4*>(xs + row * KP + c4 * 4) = v;
    }
    __syncthreads();

    const float* xr = xs + lane * KP;
    const float* wq = Wl + w * 16;
#pragma unroll 4
    for (int kp = 0; kp < KS / 4; ++kp) {
      float4 xv = *reinterpret_cast<const float4*>(xr + kp * 4);
#pragma unroll
      for (int q = 0; q < 4; ++q) {
        int k = kp * 4 + q;
        float xq = (q == 0) ? xv.x : (q == 1) ? xv.y : (q == 2) ? xv.z : xv.w;
        const float* wk = wq + k * 64;                 // wave-uniform address
        float4 w0 = *reinterpret_cast<const float4*>(wk);
        float4 w1 = *reinterpret_cast<const float4*>(wk + 4);
        float4 w2 = *reinterpret_cast<const float4*>(wk + 8);
        float4 w3 = *reinterpret_cast<const float4*>(wk + 12);
        acc[ 0] = fmaf(xq, w0.x, acc[ 0]);
        acc[ 1] = fmaf(xq, w0.y, acc[ 1]);
        acc[ 2] = fmaf(xq, w0.z, acc[ 2]);
        acc[ 3] = fmaf(xq, w0.w, acc[ 3]);
        acc[ 4] = fmaf(xq, w1.x, acc[ 4]);
        acc[ 5] = fmaf(xq, w1.y, acc[ 5]);
        acc[ 6] = fmaf(xq, w1.z, acc[ 6]);
        acc[ 7] = fmaf(xq, w1.w, acc[ 7]);
        acc[ 8] = fmaf(xq, w2.x, acc[ 8]);
        acc[ 9] = fmaf(xq, w2.y, acc[ 9]);
        acc[10] = fmaf(xq, w2.z, acc[10]);
        acc[11] = fmaf(xq, w2.w, acc[11]);
        acc[12] = fmaf(xq, w3.x, acc[12]);
        acc[13] = fmaf(xq, w3.y, acc[13]);
        acc[14] = fmaf(xq, w3.z, acc[14]);
        acc[15] = fmaf(xq, w3.w, acc[15]);
      }
    }
    __syncthreads();   // before next half restages
  }

  int node = n0 + lane;
  if (node < N) {
    float dv = dinv[node];
    unsigned pk[8];
#pragma unroll
    for (int j = 0; j < 8; ++j) {
      unsigned lo = f2bf(acc[2 * j] * dv);
      unsigned hi = f2bf(acc[2 * j + 1] * dv);
      pk[j] = lo | (hi << 16);
    }
    unsigned* op = reinterpret_cast<unsigned*>(out + (size_t)node * 64 + w * 16);
    *reinterpret_cast<uint4*>(op)     = make_uint4(pk[0], pk[1], pk[2], pk[3]);
    *reinterpret_cast<uint4*>(op + 4) = make_uint4(pk[4], pk[5], pk[6], pk[7]);
  }
}

// out[i][c] = relu( dinv[i]*(hs[i][c] + sum_{s} hs[s][c]) + bias[c] ), hs bf16.
// 16-deep batched gather: 16 uniform csr reads + 16 independent row loads
// before any add -> MLP 16/wave.
__global__ __launch_bounds__(256) void k_gather(const unsigned short* __restrict__ hs,
                                                const int* __restrict__ row_off,
                                                const int* __restrict__ csr,
                                                const float* __restrict__ dinv,
                                                const float* __restrict__ bias,
                                                float* __restrict__ out, int N) {
  const int c = threadIdx.x & 63;
  int wid = blockIdx.x * 4 + (threadIdx.x >> 6);
  int stride = gridDim.x * 4;
  float bc = bias[c];
  for (int i = wid; i < N; i += stride) {
    float acc = bf2f(hs[(((unsigned)i) << 6) + c]);   // self-loop term
    const int s0 = row_off[i], s1 = row_off[i + 1];
    int j = s0;
    for (; j + 16 <= s1; j += 16) {
      int idx[16];
#pragma unroll
      for (int q = 0; q < 16; ++q) idx[q] = csr[j + q];          // uniform, L1
      float v[16];
#pragma unroll
      for (int q = 0; q < 16; ++q)
        v[q] = bf2f(hs[(((unsigned)idx[q]) << 6) + c]);          // 16 in flight
#pragma unroll
      for (int q = 0; q < 16; ++q) acc += v[q];
    }
    if (j < s1) {                                                // clamped tail
      int idx[16];
#pragma unroll
      for (int q = 0; q < 16; ++q) idx[q] = csr[min(j + q, s1 - 1)];
      float v[16];
#pragma unroll
      for (int q = 0; q < 16; ++q)
        v[q] = bf2f(hs[(((unsigned)idx[q]) << 6) + c]);
#pragma unroll
      for (int q = 0; q < 16; ++q) acc += (j + q < s1) ? v[q] : 0.f;
    }
    out[(((unsigned)i) << 6) + c] = fmaxf(fmaf(acc, dinv[i], bc), 0.0f);
  }
}

// Stage-1 pool: 782 blocks; wave handles 16 rows; batch sorted -> graph id is
// wave-uniform and changes rarely; one fp32 atomicAdd per segment per channel.
__global__ __launch_bounds__(256) void k_pool1(const float* __restrict__ h,
                                               const int* __restrict__ batch,
                                               float* __restrict__ gsum, int N) {
  int c = threadIdx.x & 63;
  int w = threadIdx.x >> 6;
  int r0 = blockIdx.x * 64 + w * 16;
  if (r0 >= N) return;
  int r1 = min(r0 + 16, N);
  int gprev = batch[r0];
  float acc = 0.f;
  for (int r = r0; r < r1; ++r) {
    int g = batch[r];                        // wave-uniform
    if (g != gprev) { atomicAdd(&gsum[gprev * 64 + c], acc); acc = 0.f; gprev = g; }
    acc += h[(size_t)r * 64 + c];            // coalesced 256B row
  }
  atomicAdd(&gsum[gprev * 64 + c], acc);
}

__global__ void k_cnt(const int* __restrict__ batch, float* __restrict__ cinv, int N) {
  int g = threadIdx.x;   // 64 threads
  int lo = lowerb(batch, N, g);
  int hi = lowerb(batch, N, g + 1);
  cinv[g] = 1.0f / fmaxf((float)(hi - lo), 1.0f);
}

__global__ void k_final(const float* __restrict__ gsum, const float* __restrict__ cinv,
                        const float* __restrict__ Wp, const float* __restrict__ bp,
                        float* __restrict__ out) {
  int idx = blockIdx.x * 256 + threadIdx.x;
  int g = idx >> 6, o = idx & 63;
  float acc = 0.f;
#pragma unroll
  for (int k = 0; k < 64; ++k) acc += gsum[g * 64 + k] * Wp[k * 64 + o];
  out[idx] = fmaf(acc, cinv[g], bp[o]);
}

extern "C" void kernel_launch(void* const* d_in, const int* in_sizes, int n_in,
                              void* d_out, int out_size, void* d_ws, size_t ws_size,
                              hipStream_t stream) {
  const float* x    = (const float*)d_in[0];
  const float* W1   = (const float*)d_in[1];
  const float* b1   = (const float*)d_in[2];
  const float* W2   = (const float*)d_in[3];
  const float* b2   = (const float*)d_in[4];
  const float* Wp   = (const float*)d_in[5];
  const float* bp   = (const float*)d_in[6];
  const int*   ei   = (const int*)d_in[7];
  const int*   batch= (const int*)d_in[8];
  float* out = (float*)d_out;

  const int N = N_NODES, E = N_EDGESC;
  const int* src  = ei;        // edge_index[0]
  const int* dstp = ei + E;    // edge_index[1]

  char* wsb = (char*)d_ws;
  size_t o = 0;
  auto alloc = [&](size_t bytes) -> void* {
    void* p = wsb + o;
    o = (o + bytes + 255) & ~(size_t)255;
    return p;
  };
  int*      gcur   = (int*)alloc(NBUCK * 4);
  int*      boff   = (int*)alloc(NBUCK * 4);
  unsigned* bbuf   = (unsigned*)alloc((size_t)NBUCK * BCAP * 4);
  int*      row_off= (int*)alloc((size_t)(N + 1) * 4);
  int*      csr    = (int*)alloc((size_t)E * 4);
  float*    dinv   = (float*)alloc((size_t)N * 4);
  unsigned short* bufBF = (unsigned short*)alloc((size_t)N * 64 * 2);
  float*    bufF   = (float*)alloc((size_t)N * 64 * 4);
  float*    gsum   = (float*)alloc(64 * 64 * 4);
  float*    cinv   = (float*)alloc(64 * 4);

  hipMemsetAsync(gcur, 0, NBUCK * 4, stream);
  hipMemsetAsync(gsum, 0, 64 * 64 * 4, stream);

  int gA = (E + CHUNK - 1) / CHUNK;   // 196
  int gN64 = (N + 63) / 64;           // 782

  k_bucket<<<gA, 256, 0, stream>>>(src, dstp, gcur, bbuf, E);
  k_bscan<<<1, 256, 0, stream>>>(gcur, boff);
  k_bsort<<<NBUCK, 256, 0, stream>>>(bbuf, gcur, boff, csr, row_off, dinv, E);

  k_gemm<128><<<gN64, 256, 0, stream>>>(x, W1, dinv, bufBF, N);
  k_gather<<<2048, 256, 0, stream>>>(bufBF, row_off, csr, dinv, b1, bufF, N);
  k_gemm<64><<<gN64, 256, 0, stream>>>(bufF, W2, dinv, bufBF, N);
  k_gather<<<2048, 256, 0, stream>>>(bufBF, row_off, csr, dinv, b2, bufF, N);

  k_pool1<<<gN64, 256, 0, stream>>>(bufF, batch, gsum, N);
  k_cnt<<<1, 64, 0, stream>>>(batch, cinv, N);
  k_final<<<16, 256, 0, stream>>>(gsum, cinv, Wp, bp, out);
}

// Round 7
// 194.760 us; speedup vs baseline: 2.8872x; 1.0649x over previous
//
#include <hip/hip_runtime.h>

#define N_NODES  50000
#define N_EDGESC 1600000
#define N_GRAPHS 64
#define NBUCK    196      // ceil(50000/256) buckets of 256 dst nodes
#define BCAP     10240    // >> E/NBUCK (8163) + 20 sigma
#define CHUNK    8192     // edges per bucketing block

static __device__ __forceinline__ unsigned short f2bf(float f) {
  unsigned u = __float_as_uint(f);
  u += 0x7FFF + ((u >> 16) & 1);          // RNE
  return (unsigned short)(u >> 16);
}
static __device__ __forceinline__ float bfLo(unsigned u) {
  return __uint_as_float(u << 16);
}
static __device__ __forceinline__ float bfHi(unsigned u) {
  return __uint_as_float(u & 0xFFFF0000u);
}

static __device__ __forceinline__ int lowerb(const int* a, int n, int v) {
  int lo = 0, hi = n;
  while (lo < hi) { int m = (lo + hi) >> 1; if (a[m] < v) lo = m + 1; else hi = m; }
  return lo;
}

// zero the per-launch scratch (replaces pathologically slow runtime blit fills)
__global__ void k_zero(int* __restrict__ gcur, float* __restrict__ gsum) {
  int t = blockIdx.x * 256 + threadIdx.x;
  if (t < NBUCK) gcur[t] = 0;
  if (t < N_GRAPHS * 64) gsum[t] = 0.f;
}

// Phase A: chunk-bucket edges by dst>>8; per-(block,bucket) runs are
// sequential -> mostly full-line writes. Entry packed (local_dst<<24)|src.
__global__ __launch_bounds__(256) void k_bucket(const int* __restrict__ src,
                                                const int* __restrict__ dst,
                                                int* __restrict__ gcur,
                                                unsigned* __restrict__ bbuf, int E) {
  __shared__ int hist[NBUCK], base[NBUCK], cur[NBUCK];
  int t = threadIdx.x;
  if (t < NBUCK) { hist[t] = 0; cur[t] = 0; }
  __syncthreads();
  int e0 = blockIdx.x * CHUNK;
  for (int i = 0; i < CHUNK; i += 256) {
    int e = e0 + i + t;
    if (e < E) atomicAdd(&hist[dst[e] >> 8], 1);
  }
  __syncthreads();
  if (t < NBUCK) base[t] = hist[t] ? atomicAdd(&gcur[t], hist[t]) : 0;
  __syncthreads();
  for (int i = 0; i < CHUNK; i += 256) {
    int e = e0 + i + t;
    if (e < E) {
      int d = dst[e], b = d >> 8;
      int pos = base[b] + atomicAdd(&cur[b], 1);
      unsigned packed = ((unsigned)(d & 255) << 24) | (unsigned)src[e];
      if (pos < BCAP) bbuf[(size_t)b * BCAP + pos] = packed;
    }
  }
}

// exclusive scan of the 196 bucket totals
__global__ void k_bscan(const int* __restrict__ gcur, int* __restrict__ boff) {
  __shared__ int sm[256];
  int t = threadIdx.x;
  int v = (t < NBUCK) ? gcur[t] : 0;
  sm[t] = v;
  __syncthreads();
  for (int o = 1; o < 256; o <<= 1) {
    int add = (t >= o) ? sm[t - o] : 0;
    __syncthreads();
    sm[t] += add;
    __syncthreads();
  }
  if (t < NBUCK) boff[t] = sm[t] - v;
}

// Phase B: per-bucket counting sort -> csr segment + row_off + dinv.
__global__ __launch_bounds__(256) void k_bsort(const unsigned* __restrict__ bbuf,
                                               const int* __restrict__ gcur,
                                               const int* __restrict__ boff,
                                               int* __restrict__ csr,
                                               int* __restrict__ row_off,
                                               float* __restrict__ dinv, int E) {
  __shared__ int hist[256], off[256], cur[256];
  int b = blockIdx.x, t = threadIdx.x;
  hist[t] = 0; cur[t] = 0;
  __syncthreads();
  int cnt = min(gcur[b], BCAP);
  const unsigned* bp = bbuf + (size_t)b * BCAP;
  for (int i = t; i < cnt; i += 256) atomicAdd(&hist[bp[i] >> 24], 1);
  __syncthreads();
  off[t] = hist[t];
  __syncthreads();
  for (int o = 1; o < 256; o <<= 1) {
    int add = (t >= o) ? off[t - o] : 0;
    __syncthreads();
    off[t] += add;
    __syncthreads();
  }
  int excl = off[t] - hist[t];
  __syncthreads();
  off[t] = excl;
  __syncthreads();
  int gb = boff[b];
  int idx = (b << 8) + t;
  if (idx <= N_NODES) row_off[idx] = gb + off[t];
  if (idx < N_NODES)  dinv[idx] = rsqrtf((float)(hist[t] + 1));  // +1 self-loop
  for (int i = t; i < cnt; i += 256) {
    unsigned v = bp[i];
    int ld = v >> 24;
    int pos = atomicAdd(&cur[ld], 1);
    csr[gb + off[ld] + pos] = (int)(v & 0xFFFFFFu);
  }
}

// out_bf16[i][c] = bf16( (x[i,:] @ W[:,c]) * dinv[i] )
// Block = 256 thr = 4 waves; K-step=64 blocking keeps LDS ~34KB -> 4 blk/CU.
template <int K>
__global__ __launch_bounds__(256) void k_gemm(const float* __restrict__ x,
                                              const float* __restrict__ W,
                                              const float* __restrict__ dinv,
                                              unsigned short* __restrict__ out, int N) {
  constexpr int KS = 64;            // K-step
  constexpr int KP = KS + 4;        // padded xs row stride
  __shared__ float xs[64 * KP];     // 17.4 KB
  __shared__ float Wl[KS * 64];     // 16 KB
  const int t = threadIdx.x;
  const int lane = t & 63;
  const int w = t >> 6;
  const int n0 = blockIdx.x * 64;

  float acc[16];
#pragma unroll
  for (int j = 0; j < 16; ++j) acc[j] = 0.f;

  for (int h = 0; h < K / KS; ++h) {
#pragma unroll
    for (int i = 0; i < KS * 16 / 256; ++i) {
      int li = i * 256 + t;
      float4 v = reinterpret_cast<const float4*>(W + h * KS * 64)[li];
      *reinterpret_cast<float4*>(Wl + li * 4) = v;
    }
#pragma unroll
    for (int i = 0; i < 64 * (KS / 4) / 256; ++i) {
      int li = i * 256 + t;
      int row = li / (KS / 4), c4 = li % (KS / 4);
      int node = n0 + row;
      float4 v = make_float4(0.f, 0.f, 0.f, 0.f);
      if (node < N) v = reinterpret_cast<const float4*>(x + (size_t)node * K + h * KS)[c4];
      *reinterpret_cast<float4*>(xs + row * KP + c4 * 4) = v;
    }
    __syncthreads();

    const float* xr = xs + lane * KP;
    const float* wq = Wl + w * 16;
#pragma unroll 4
    for (int kp = 0; kp < KS / 4; ++kp) {
      float4 xv = *reinterpret_cast<const float4*>(xr + kp * 4);
#pragma unroll
      for (int q = 0; q < 4; ++q) {
        int k = kp * 4 + q;
        float xq = (q == 0) ? xv.x : (q == 1) ? xv.y : (q == 2) ? xv.z : xv.w;
        const float* wk = wq + k * 64;                 // wave-uniform address
        float4 w0 = *reinterpret_cast<const float4*>(wk);
        float4 w1 = *reinterpret_cast<const float4*>(wk + 4);
        float4 w2 = *reinterpret_cast<const float4*>(wk + 8);
        float4 w3 = *reinterpret_cast<const float4*>(wk + 12);
        acc[ 0] = fmaf(xq, w0.x, acc[ 0]);
        acc[ 1] = fmaf(xq, w0.y, acc[ 1]);
        acc[ 2] = fmaf(xq, w0.z, acc[ 2]);
        acc[ 3] = fmaf(xq, w0.w, acc[ 3]);
        acc[ 4] = fmaf(xq, w1.x, acc[ 4]);
        acc[ 5] = fmaf(xq, w1.y, acc[ 5]);
        acc[ 6] = fmaf(xq, w1.z, acc[ 6]);
        acc[ 7] = fmaf(xq, w1.w, acc[ 7]);
        acc[ 8] = fmaf(xq, w2.x, acc[ 8]);
        acc[ 9] = fmaf(xq, w2.y, acc[ 9]);
        acc[10] = fmaf(xq, w2.z, acc[10]);
        acc[11] = fmaf(xq, w2.w, acc[11]);
        acc[12] = fmaf(xq, w3.x, acc[12]);
        acc[13] = fmaf(xq, w3.y, acc[13]);
        acc[14] = fmaf(xq, w3.z, acc[14]);
        acc[15] = fmaf(xq, w3.w, acc[15]);
      }
    }
    __syncthreads();   // before next half restages
  }

  int node = n0 + lane;
  if (node < N) {
    float dv = dinv[node];
    unsigned pk[8];
#pragma unroll
    for (int j = 0; j < 8; ++j) {
      unsigned lo = f2bf(acc[2 * j] * dv);
      unsigned hi = f2bf(acc[2 * j + 1] * dv);
      pk[j] = lo | (hi << 16);
    }
    unsigned* op = reinterpret_cast<unsigned*>(out + (size_t)node * 64 + w * 16);
    *reinterpret_cast<uint4*>(op)     = make_uint4(pk[0], pk[1], pk[2], pk[3]);
    *reinterpret_cast<uint4*>(op + 4) = make_uint4(pk[4], pk[5], pk[6], pk[7]);
  }
}

// out[i][c] = relu( dinv[i]*(hs[i][c] + sum_{s} hs[s][c]) + bias[c] ), hs bf16.
// Dual-row dword gather: lanes 0-31 = edge 2q (row as 32 packed dwords),
// lanes 32-63 = edge 2q+1. 16 loads in flight cover 32 edges; one
// shfl_xor(32) folds the halves at the end. Halves per-edge VALU vs ushort.
__global__ __launch_bounds__(256) void k_gather(const unsigned short* __restrict__ hs,
                                                const int* __restrict__ row_off,
                                                const int* __restrict__ csr,
                                                const float* __restrict__ dinv,
                                                const float* __restrict__ bias,
                                                float* __restrict__ out, int N) {
  const int lane = threadIdx.x & 63;
  const int half = lane >> 5;        // which edge of the pair
  const int cl   = lane & 31;        // dword (channel pair) within row
  int wid = blockIdx.x * 4 + (threadIdx.x >> 6);
  int stride = gridDim.x * 4;
  const unsigned* hsd = reinterpret_cast<const unsigned*>(hs);
  float b0 = bias[2 * cl], b1 = bias[2 * cl + 1];
  for (int i = wid; i < N; i += stride) {
    float acc0 = 0.f, acc1 = 0.f;
    {  // self-loop term, counted once (half 0 only)
      unsigned sd = hsd[(((unsigned)i) << 5) + cl];
      if (half == 0) { acc0 = bfLo(sd); acc1 = bfHi(sd); }
    }
    const int s0 = row_off[i], s1 = row_off[i + 1];
    int j = s0;
    for (; j + 32 <= s1; j += 32) {
      int idx[16];
#pragma unroll
      for (int q = 0; q < 16; ++q) idx[q] = csr[j + 2 * q + half];
      unsigned v[16];
#pragma unroll
      for (int q = 0; q < 16; ++q)
        v[q] = hsd[(((unsigned)idx[q]) << 5) + cl];    // 16 x 256B in flight
#pragma unroll
      for (int q = 0; q < 16; ++q) { acc0 += bfLo(v[q]); acc1 += bfHi(v[q]); }
    }
    if (j < s1) {                                      // clamped masked tail
      int idx[16];
      bool ok[16];
#pragma unroll
      for (int q = 0; q < 16; ++q) {
        int e = j + 2 * q + half;
        ok[q] = e < s1;
        idx[q] = csr[min(e, s1 - 1)];
      }
      unsigned v[16];
#pragma unroll
      for (int q = 0; q < 16; ++q)
        v[q] = hsd[(((unsigned)idx[q]) << 5) + cl];
#pragma unroll
      for (int q = 0; q < 16; ++q) {
        if (ok[q]) { acc0 += bfLo(v[q]); acc1 += bfHi(v[q]); }
      }
    }
    acc0 += __shfl_xor(acc0, 32);
    acc1 += __shfl_xor(acc1, 32);
    if (half == 0) {
      float dv = dinv[i];
      float r0 = fmaxf(fmaf(acc0, dv, b0), 0.0f);
      float r1 = fmaxf(fmaf(acc1, dv, b1), 0.0f);
      *reinterpret_cast<float2*>(out + (((size_t)i) << 6) + 2 * cl) = make_float2(r0, r1);
    }
  }
}

// Stage-1 pool: wave handles 16 rows; batch sorted -> graph id wave-uniform;
// one fp32 atomicAdd per segment per channel.
__global__ __launch_bounds__(256) void k_pool1(const float* __restrict__ h,
                                               const int* __restrict__ batch,
                                               float* __restrict__ gsum, int N) {
  int c = threadIdx.x & 63;
  int w = threadIdx.x >> 6;
  int r0 = blockIdx.x * 64 + w * 16;
  if (r0 >= N) return;
  int r1 = min(r0 + 16, N);
  int gprev = batch[r0];
  float acc = 0.f;
  for (int r = r0; r < r1; ++r) {
    int g = batch[r];                        // wave-uniform
    if (g != gprev) { atomicAdd(&gsum[gprev * 64 + c], acc); acc = 0.f; gprev = g; }
    acc += h[(size_t)r * 64 + c];            // coalesced 256B row
  }
  atomicAdd(&gsum[gprev * 64 + c], acc);
}

__global__ void k_cnt(const int* __restrict__ batch, float* __restrict__ cinv, int N) {
  int g = threadIdx.x;   // 64 threads
  int lo = lowerb(batch, N, g);
  int hi = lowerb(batch, N, g + 1);
  cinv[g] = 1.0f / fmaxf((float)(hi - lo), 1.0f);
}

__global__ void k_final(const float* __restrict__ gsum, const float* __restrict__ cinv,
                        const float* __restrict__ Wp, const float* __restrict__ bp,
                        float* __restrict__ out) {
  int idx = blockIdx.x * 256 + threadIdx.x;
  int g = idx >> 6, o = idx & 63;
  float acc = 0.f;
#pragma unroll
  for (int k = 0; k < 64; ++k) acc += gsum[g * 64 + k] * Wp[k * 64 + o];
  out[idx] = fmaf(acc, cinv[g], bp[o]);
}

extern "C" void kernel_launch(void* const* d_in, const int* in_sizes, int n_in,
                              void* d_out, int out_size, void* d_ws, size_t ws_size,
                              hipStream_t stream) {
  const float* x    = (const float*)d_in[0];
  const float* W1   = (const float*)d_in[1];
  const float* b1   = (const float*)d_in[2];
  const float* W2   = (const float*)d_in[3];
  const float* b2   = (const float*)d_in[4];
  const float* Wp   = (const float*)d_in[5];
  const float* bp   = (const float*)d_in[6];
  const int*   ei   = (const int*)d_in[7];
  const int*   batch= (const int*)d_in[8];
  float* out = (float*)d_out;

  const int N = N_NODES, E = N_EDGESC;
  const int* src  = ei;        // edge_index[0]
  const int* dstp = ei + E;    // edge_index[1]

  char* wsb = (char*)d_ws;
  size_t o = 0;
  auto alloc = [&](size_t bytes) -> void* {
    void* p = wsb + o;
    o = (o + bytes + 255) & ~(size_t)255;
    return p;
  };
  int*      gcur   = (int*)alloc(NBUCK * 4);
  int*      boff   = (int*)alloc(NBUCK * 4);
  unsigned* bbuf   = (unsigned*)alloc((size_t)NBUCK * BCAP * 4);
  int*      row_off= (int*)alloc((size_t)(N + 1) * 4);
  int*      csr    = (int*)alloc((size_t)E * 4);
  float*    dinv   = (float*)alloc((size_t)N * 4);
  unsigned short* bufBF = (unsigned short*)alloc((size_t)N * 64 * 2);
  float*    bufF   = (float*)alloc((size_t)N * 64 * 4);
  float*    gsum   = (float*)alloc(64 * 64 * 4);
  float*    cinv   = (float*)alloc(64 * 4);

  int gA = (E + CHUNK - 1) / CHUNK;   // 196
  int gN64 = (N + 63) / 64;           // 782

  k_zero<<<(N_GRAPHS * 64 + 255) / 256, 256, 0, stream>>>(gcur, gsum);
  k_bucket<<<gA, 256, 0, stream>>>(src, dstp, gcur, bbuf, E);
  k_bscan<<<1, 256, 0, stream>>>(gcur, boff);
  k_bsort<<<NBUCK, 256, 0, stream>>>(bbuf, gcur, boff, csr, row_off, dinv, E);

  k_gemm<128><<<gN64, 256, 0, stream>>>(x, W1, dinv, bufBF, N);
  k_gather<<<2048, 256, 0, stream>>>(bufBF, row_off, csr, dinv, b1, bufF, N);
  k_gemm<64><<<gN64, 256, 0, stream>>>(bufF, W2, dinv, bufBF, N);
  k_gather<<<2048, 256, 0, stream>>>(bufBF, row_off, csr, dinv, b2, bufF, N);

  k_pool1<<<gN64, 256, 0, stream>>>(bufF, batch, gsum, N);
  k_cnt<<<1, 64, 0, stream>>>(batch, cinv, N);
  k_final<<<16, 256, 0, stream>>>(gsum, cinv, Wp, bp, out);
}

// Round 8
// 192.515 us; speedup vs baseline: 2.9209x; 1.0117x over previous
//
#include <hip/hip_runtime.h>

#define N_NODES  50000
#define N_EDGESC 1600000
#define N_GRAPHS 64
#define NBUCK    196      // ceil(50000/256) buckets of 256 dst nodes
#define BCAP     10240    // >> E/NBUCK (8163) + 20 sigma
#define CHUNK    2048     // edges per bucketing block -> 782 blocks (~3/CU)

static __device__ __forceinline__ unsigned short f2bf(float f) {
  unsigned u = __float_as_uint(f);
  u += 0x7FFF + ((u >> 16) & 1);          // RNE
  return (unsigned short)(u >> 16);
}
static __device__ __forceinline__ float bfLo(unsigned u) {
  return __uint_as_float(u << 16);
}
static __device__ __forceinline__ float bfHi(unsigned u) {
  return __uint_as_float(u & 0xFFFF0000u);
}

static __device__ __forceinline__ int lowerb(const int* a, int n, int v) {
  int lo = 0, hi = n;
  while (lo < hi) { int m = (lo + hi) >> 1; if (a[m] < v) lo = m + 1; else hi = m; }
  return lo;
}

// zero the per-launch scratch (replaces pathologically slow runtime blit fills)
__global__ void k_zero(int* __restrict__ gcur, float* __restrict__ gsum) {
  int t = blockIdx.x * 256 + threadIdx.x;
  if (t < NBUCK) gcur[t] = 0;
  if (t < N_GRAPHS * 64) gsum[t] = 0.f;
}

// Phase A: chunk-bucket edges by dst>>8; per-(block,bucket) runs are
// sequential -> mostly full-line writes. Entry packed (local_dst<<24)|src.
__global__ __launch_bounds__(256) void k_bucket(const int* __restrict__ src,
                                                const int* __restrict__ dst,
                                                int* __restrict__ gcur,
                                                unsigned* __restrict__ bbuf, int E) {
  __shared__ int hist[NBUCK], base[NBUCK], cur[NBUCK];
  int t = threadIdx.x;
  if (t < NBUCK) { hist[t] = 0; cur[t] = 0; }
  __syncthreads();
  int e0 = blockIdx.x * CHUNK;
#pragma unroll
  for (int i = 0; i < CHUNK; i += 256) {
    int e = e0 + i + t;
    if (e < E) atomicAdd(&hist[dst[e] >> 8], 1);
  }
  __syncthreads();
  if (t < NBUCK) base[t] = hist[t] ? atomicAdd(&gcur[t], hist[t]) : 0;
  __syncthreads();
#pragma unroll
  for (int i = 0; i < CHUNK; i += 256) {
    int e = e0 + i + t;
    if (e < E) {
      int d = dst[e], b = d >> 8;
      int pos = base[b] + atomicAdd(&cur[b], 1);
      unsigned packed = ((unsigned)(d & 255) << 24) | (unsigned)src[e];
      if (pos < BCAP) bbuf[(size_t)b * BCAP + pos] = packed;
    }
  }
}

// exclusive scan of the 196 bucket totals
__global__ void k_bscan(const int* __restrict__ gcur, int* __restrict__ boff) {
  __shared__ int sm[256];
  int t = threadIdx.x;
  int v = (t < NBUCK) ? gcur[t] : 0;
  sm[t] = v;
  __syncthreads();
  for (int o = 1; o < 256; o <<= 1) {
    int add = (t >= o) ? sm[t - o] : 0;
    __syncthreads();
    sm[t] += add;
    __syncthreads();
  }
  if (t < NBUCK) boff[t] = sm[t] - v;
}

// Phase B: per-bucket counting sort -> csr segment + row_off + dinv.
__global__ __launch_bounds__(256) void k_bsort(const unsigned* __restrict__ bbuf,
                                               const int* __restrict__ gcur,
                                               const int* __restrict__ boff,
                                               int* __restrict__ csr,
                                               int* __restrict__ row_off,
                                               float* __restrict__ dinv, int E) {
  __shared__ int hist[256], off[256], cur[256];
  int b = blockIdx.x, t = threadIdx.x;
  hist[t] = 0; cur[t] = 0;
  __syncthreads();
  int cnt = min(gcur[b], BCAP);
  const unsigned* bp = bbuf + (size_t)b * BCAP;
  for (int i = t; i < cnt; i += 256) atomicAdd(&hist[bp[i] >> 24], 1);
  __syncthreads();
  off[t] = hist[t];
  __syncthreads();
  for (int o = 1; o < 256; o <<= 1) {
    int add = (t >= o) ? off[t - o] : 0;
    __syncthreads();
    off[t] += add;
    __syncthreads();
  }
  int excl = off[t] - hist[t];
  __syncthreads();
  off[t] = excl;
  __syncthreads();
  int gb = boff[b];
  int idx = (b << 8) + t;
  if (idx <= N_NODES) row_off[idx] = gb + off[t];
  if (idx < N_NODES)  dinv[idx] = rsqrtf((float)(hist[t] + 1));  // +1 self-loop
  for (int i = t; i < cnt; i += 256) {
    unsigned v = bp[i];
    int ld = v >> 24;
    int pos = atomicAdd(&cur[ld], 1);
    csr[gb + off[ld] + pos] = (int)(v & 0xFFFFFFu);
  }
}

// out_bf16[i][c] = bf16( (x[i,:] @ W[:,c]) * dinv[i] )
// Block = 256 thr = 4 waves; K-step=64 blocking keeps LDS ~34KB -> 4 blk/CU.
template <int K>
__global__ __launch_bounds__(256) void k_gemm(const float* __restrict__ x,
                                              const float* __restrict__ W,
                                              const float* __restrict__ dinv,
                                              unsigned short* __restrict__ out, int N) {
  constexpr int KS = 64;            // K-step
  constexpr int KP = KS + 4;        // padded xs row stride
  __shared__ float xs[64 * KP];     // 17.4 KB
  __shared__ float Wl[KS * 64];     // 16 KB
  const int t = threadIdx.x;
  const int lane = t & 63;
  const int w = t >> 6;
  const int n0 = blockIdx.x * 64;

  float acc[16];
#pragma unroll
  for (int j = 0; j < 16; ++j) acc[j] = 0.f;

  for (int h = 0; h < K / KS; ++h) {
#pragma unroll
    for (int i = 0; i < KS * 16 / 256; ++i) {
      int li = i * 256 + t;
      float4 v = reinterpret_cast<const float4*>(W + h * KS * 64)[li];
      *reinterpret_cast<float4*>(Wl + li * 4) = v;
    }
#pragma unroll
    for (int i = 0; i < 64 * (KS / 4) / 256; ++i) {
      int li = i * 256 + t;
      int row = li / (KS / 4), c4 = li % (KS / 4);
      int node = n0 + row;
      float4 v = make_float4(0.f, 0.f, 0.f, 0.f);
      if (node < N) v = reinterpret_cast<const float4*>(x + (size_t)node * K + h * KS)[c4];
      *reinterpret_cast<float4*>(xs + row * KP + c4 * 4) = v;
    }
    __syncthreads();

    const float* xr = xs + lane * KP;
    const float* wq = Wl + w * 16;
#pragma unroll 4
    for (int kp = 0; kp < KS / 4; ++kp) {
      float4 xv = *reinterpret_cast<const float4*>(xr + kp * 4);
#pragma unroll
      for (int q = 0; q < 4; ++q) {
        int k = kp * 4 + q;
        float xq = (q == 0) ? xv.x : (q == 1) ? xv.y : (q == 2) ? xv.z : xv.w;
        const float* wk = wq + k * 64;                 // wave-uniform address
        float4 w0 = *reinterpret_cast<const float4*>(wk);
        float4 w1 = *reinterpret_cast<const float4*>(wk + 4);
        float4 w2 = *reinterpret_cast<const float4*>(wk + 8);
        float4 w3 = *reinterpret_cast<const float4*>(wk + 12);
        acc[ 0] = fmaf(xq, w0.x, acc[ 0]);
        acc[ 1] = fmaf(xq, w0.y, acc[ 1]);
        acc[ 2] = fmaf(xq, w0.z, acc[ 2]);
        acc[ 3] = fmaf(xq, w0.w, acc[ 3]);
        acc[ 4] = fmaf(xq, w1.x, acc[ 4]);
        acc[ 5] = fmaf(xq, w1.y, acc[ 5]);
        acc[ 6] = fmaf(xq, w1.z, acc[ 6]);
        acc[ 7] = fmaf(xq, w1.w, acc[ 7]);
        acc[ 8] = fmaf(xq, w2.x, acc[ 8]);
        acc[ 9] = fmaf(xq, w2.y, acc[ 9]);
        acc[10] = fmaf(xq, w2.z, acc[10]);
        acc[11] = fmaf(xq, w2.w, acc[11]);
        acc[12] = fmaf(xq, w3.x, acc[12]);
        acc[13] = fmaf(xq, w3.y, acc[13]);
        acc[14] = fmaf(xq, w3.z, acc[14]);
        acc[15] = fmaf(xq, w3.w, acc[15]);
      }
    }
    __syncthreads();   // before next half restages
  }

  int node = n0 + lane;
  if (node < N) {
    float dv = dinv[node];
    unsigned pk[8];
#pragma unroll
    for (int j = 0; j < 8; ++j) {
      unsigned lo = f2bf(acc[2 * j] * dv);
      unsigned hi = f2bf(acc[2 * j + 1] * dv);
      pk[j] = lo | (hi << 16);
    }
    unsigned* op = reinterpret_cast<unsigned*>(out + (size_t)node * 64 + w * 16);
    *reinterpret_cast<uint4*>(op)     = make_uint4(pk[0], pk[1], pk[2], pk[3]);
    *reinterpret_cast<uint4*>(op + 4) = make_uint4(pk[4], pk[5], pk[6], pk[7]);
  }
}

// out[i][c] = relu( dinv[i]*(hs[i][c] + sum_{s} hs[s][c]) + bias[c] ), hs bf16.
// Dual-row dword gather: lanes 0-31 = edge 2q, lanes 32-63 = edge 2q+1;
// 16 loads in flight cover 32 edges; shfl_xor(32) folds halves at the end.
__global__ __launch_bounds__(256) void k_gather(const unsigned short* __restrict__ hs,
                                                const int* __restrict__ row_off,
                                                const int* __restrict__ csr,
                                                const float* __restrict__ dinv,
                                                const float* __restrict__ bias,
                                                float* __restrict__ out, int N) {
  const int lane = threadIdx.x & 63;
  const int half = lane >> 5;        // which edge of the pair
  const int cl   = lane & 31;        // dword (channel pair) within row
  int wid = blockIdx.x * 4 + (threadIdx.x >> 6);
  int stride = gridDim.x * 4;
  const unsigned* hsd = reinterpret_cast<const unsigned*>(hs);
  float b0 = bias[2 * cl], b1 = bias[2 * cl + 1];
  for (int i = wid; i < N; i += stride) {
    float acc0 = 0.f, acc1 = 0.f;
    {  // self-loop term, counted once (half 0 only)
      unsigned sd = hsd[(((unsigned)i) << 5) + cl];
      if (half == 0) { acc0 = bfLo(sd); acc1 = bfHi(sd); }
    }
    const int s0 = row_off[i], s1 = row_off[i + 1];
    int j = s0;
    for (; j + 32 <= s1; j += 32) {
      int idx[16];
#pragma unroll
      for (int q = 0; q < 16; ++q) idx[q] = csr[j + 2 * q + half];
      unsigned v[16];
#pragma unroll
      for (int q = 0; q < 16; ++q)
        v[q] = hsd[(((unsigned)idx[q]) << 5) + cl];    // 16 x 256B in flight
#pragma unroll
      for (int q = 0; q < 16; ++q) { acc0 += bfLo(v[q]); acc1 += bfHi(v[q]); }
    }
    if (j < s1) {                                      // clamped masked tail
      int idx[16];
      bool ok[16];
#pragma unroll
      for (int q = 0; q < 16; ++q) {
        int e = j + 2 * q + half;
        ok[q] = e < s1;
        idx[q] = csr[min(e, s1 - 1)];
      }
      unsigned v[16];
#pragma unroll
      for (int q = 0; q < 16; ++q)
        v[q] = hsd[(((unsigned)idx[q]) << 5) + cl];
#pragma unroll
      for (int q = 0; q < 16; ++q) {
        if (ok[q]) { acc0 += bfLo(v[q]); acc1 += bfHi(v[q]); }
      }
    }
    acc0 += __shfl_xor(acc0, 32);
    acc1 += __shfl_xor(acc1, 32);
    if (half == 0) {
      float dv = dinv[i];
      float r0 = fmaxf(fmaf(acc0, dv, b0), 0.0f);
      float r1 = fmaxf(fmaf(acc1, dv, b1), 0.0f);
      *reinterpret_cast<float2*>(out + (((size_t)i) << 6) + 2 * cl) = make_float2(r0, r1);
    }
  }
}

// Stage-1 pool: wave handles 16 rows; batch sorted -> graph id wave-uniform;
// one fp32 atomicAdd per segment per channel.
__global__ __launch_bounds__(256) void k_pool1(const float* __restrict__ h,
                                               const int* __restrict__ batch,
                                               float* __restrict__ gsum, int N) {
  int c = threadIdx.x & 63;
  int w = threadIdx.x >> 6;
  int r0 = blockIdx.x * 64 + w * 16;
  if (r0 >= N) return;
  int r1 = min(r0 + 16, N);
  int gprev = batch[r0];
  float acc = 0.f;
  for (int r = r0; r < r1; ++r) {
    int g = batch[r];                        // wave-uniform
    if (g != gprev) { atomicAdd(&gsum[gprev * 64 + c], acc); acc = 0.f; gprev = g; }
    acc += h[(size_t)r * 64 + c];            // coalesced 256B row
  }
  atomicAdd(&gsum[gprev * 64 + c], acc);
}

__global__ void k_cnt(const int* __restrict__ batch, float* __restrict__ cinv, int N) {
  int g = threadIdx.x;   // 64 threads
  int lo = lowerb(batch, N, g);
  int hi = lowerb(batch, N, g + 1);
  cinv[g] = 1.0f / fmaxf((float)(hi - lo), 1.0f);
}

__global__ void k_final(const float* __restrict__ gsum, const float* __restrict__ cinv,
                        const float* __restrict__ Wp, const float* __restrict__ bp,
                        float* __restrict__ out) {
  int idx = blockIdx.x * 256 + threadIdx.x;
  int g = idx >> 6, o = idx & 63;
  float acc = 0.f;
#pragma unroll
  for (int k = 0; k < 64; ++k) acc += gsum[g * 64 + k] * Wp[k * 64 + o];
  out[idx] = fmaf(acc, cinv[g], bp[o]);
}

extern "C" void kernel_launch(void* const* d_in, const int* in_sizes, int n_in,
                              void* d_out, int out_size, void* d_ws, size_t ws_size,
                              hipStream_t stream) {
  const float* x    = (const float*)d_in[0];
  const float* W1   = (const float*)d_in[1];
  const float* b1   = (const float*)d_in[2];
  const float* W2   = (const float*)d_in[3];
  const float* b2   = (const float*)d_in[4];
  const float* Wp   = (const float*)d_in[5];
  const float* bp   = (const float*)d_in[6];
  const int*   ei   = (const int*)d_in[7];
  const int*   batch= (const int*)d_in[8];
  float* out = (float*)d_out;

  const int N = N_NODES, E = N_EDGESC;
  const int* src  = ei;        // edge_index[0]
  const int* dstp = ei + E;    // edge_index[1]

  char* wsb = (char*)d_ws;
  size_t o = 0;
  auto alloc = [&](size_t bytes) -> void* {
    void* p = wsb + o;
    o = (o + bytes + 255) & ~(size_t)255;
    return p;
  };
  int*      gcur   = (int*)alloc(NBUCK * 4);
  int*      boff   = (int*)alloc(NBUCK * 4);
  unsigned* bbuf   = (unsigned*)alloc((size_t)NBUCK * BCAP * 4);
  int*      row_off= (int*)alloc((size_t)(N + 1) * 4);
  int*      csr    = (int*)alloc((size_t)E * 4);
  float*    dinv   = (float*)alloc((size_t)N * 4);
  unsigned short* bufBF = (unsigned short*)alloc((size_t)N * 64 * 2);
  float*    bufF   = (float*)alloc((size_t)N * 64 * 4);
  float*    gsum   = (float*)alloc(64 * 64 * 4);
  float*    cinv   = (float*)alloc(64 * 4);

  int gA = (E + CHUNK - 1) / CHUNK;   // 782
  int gN64 = (N + 63) / 64;           // 782

  k_zero<<<(N_GRAPHS * 64 + 255) / 256, 256, 0, stream>>>(gcur, gsum);
  k_bucket<<<gA, 256, 0, stream>>>(src, dstp, gcur, bbuf, E);
  k_bscan<<<1, 256, 0, stream>>>(gcur, boff);
  k_bsort<<<NBUCK, 256, 0, stream>>>(bbuf, gcur, boff, csr, row_off, dinv, E);

  k_gemm<128><<<gN64, 256, 0, stream>>>(x, W1, dinv, bufBF, N);
  k_gather<<<2048, 256, 0, stream>>>(bufBF, row_off, csr, dinv, b1, bufF, N);
  k_gemm<64><<<gN64, 256, 0, stream>>>(bufF, W2, dinv, bufBF, N);
  k_gather<<<2048, 256, 0, stream>>>(bufBF, row_off, csr, dinv, b2, bufF, N);

  k_pool1<<<gN64, 256, 0, stream>>>(bufF, batch, gsum, N);
  k_cnt<<<1, 64, 0, stream>>>(batch, cinv, N);
  k_final<<<16, 256, 0, stream>>>(gsum, cinv, Wp, bp, out);
}

// Round 9
// 173.145 us; speedup vs baseline: 3.2476x; 1.1119x over previous
//
#include <hip/hip_runtime.h>

#define N_NODES  50000
#define N_EDGESC 1600000
#define N_GRAPHS 64
#define NBUCK    196      // ceil(50000/256) buckets of 256 dst nodes
#define CHUNK    2048     // edges per hist/scatter block
#define NBLK     782      // ceil(E/CHUNK)

static __device__ __forceinline__ unsigned short f2bf(float f) {
  unsigned u = __float_as_uint(f);
  u += 0x7FFF + ((u >> 16) & 1);          // RNE
  return (unsigned short)(u >> 16);
}
static __device__ __forceinline__ float bfLo(unsigned u) {
  return __uint_as_float(u << 16);
}
static __device__ __forceinline__ float bfHi(unsigned u) {
  return __uint_as_float(u & 0xFFFF0000u);
}

static __device__ __forceinline__ int lowerb(const int* a, int n, int v) {
  int lo = 0, hi = n;
  while (lo < hi) { int m = (lo + hi) >> 1; if (a[m] < v) lo = m + 1; else hi = m; }
  return lo;
}

// Pass 1: per-block bucket histogram (LDS only) -> bcnt[bucket][blk].
// Block 0 also zeros gsum (replaces k_zero launch).
__global__ __launch_bounds__(256) void k_hist(const int* __restrict__ dst,
                                              int* __restrict__ bcnt,
                                              float* __restrict__ gsum, int E) {
  __shared__ int hist[NBUCK];
  int t = threadIdx.x, blk = blockIdx.x;
  if (t < NBUCK) hist[t] = 0;
  if (blk == 0) {
    for (int i = t; i < N_GRAPHS * 64; i += 256) gsum[i] = 0.f;
  }
  __syncthreads();
  int e0 = blk * CHUNK;
#pragma unroll
  for (int i = 0; i < CHUNK; i += 256) {
    int e = e0 + i + t;
    if (e < E) atomicAdd(&hist[dst[e] >> 8], 1);
  }
  __syncthreads();
  if (t < NBUCK) bcnt[(size_t)t * NBLK + blk] = hist[t];
}

// Pass 2: per-bucket exclusive scan across blocks (in place) + bucket totals.
__global__ __launch_bounds__(256) void k_cscan(int* __restrict__ bcnt,
                                               int* __restrict__ btot) {
  __shared__ int sm[256];
  int b = blockIdx.x, t = threadIdx.x;
  int* p = bcnt + (size_t)b * NBLK;
  int carry = 0;
  for (int tile = 0; tile < (NBLK + 255) / 256; ++tile) {
    int idx = tile * 256 + t;
    int v = (idx < NBLK) ? p[idx] : 0;
    sm[t] = v;
    __syncthreads();
    for (int o = 1; o < 256; o <<= 1) {
      int add = (t >= o) ? sm[t - o] : 0;
      __syncthreads();
      sm[t] += add;
      __syncthreads();
    }
    int incl = sm[t];
    int total = sm[255];
    if (idx < NBLK) p[idx] = incl - v + carry;
    carry += total;
    __syncthreads();
  }
  if (t == 0) btot[b] = carry;
}

// Pass 3: scatter edges to final bucket-contiguous positions (no global
// atomics; in-LDS 196-scan of btot recomputed per block).
__global__ __launch_bounds__(256) void k_scatter(const int* __restrict__ src,
                                                 const int* __restrict__ dst,
                                                 const int* __restrict__ bcnt,
                                                 const int* __restrict__ btot,
                                                 unsigned* __restrict__ bbuf, int E) {
  __shared__ int base[NBUCK], cur[NBUCK], sm[256];
  int t = threadIdx.x, blk = blockIdx.x;
  int v = (t < NBUCK) ? btot[t] : 0;
  sm[t] = v;
  __syncthreads();
  for (int o = 1; o < 256; o <<= 1) {
    int add = (t >= o) ? sm[t - o] : 0;
    __syncthreads();
    sm[t] += add;
    __syncthreads();
  }
  if (t < NBUCK) {
    base[t] = (sm[t] - v) + bcnt[(size_t)t * NBLK + blk];
    cur[t] = 0;
  }
  __syncthreads();
  int e0 = blk * CHUNK;
#pragma unroll
  for (int i = 0; i < CHUNK; i += 256) {
    int e = e0 + i + t;
    if (e < E) {
      int d = dst[e], b = d >> 8;
      int pos = base[b] + atomicAdd(&cur[b], 1);
      bbuf[pos] = ((unsigned)(d & 255) << 24) | (unsigned)src[e];
    }
  }
}

// Pass 4: per-bucket counting sort -> csr + row_off + dinv. 512 threads.
__global__ __launch_bounds__(512) void k_bsort(const unsigned* __restrict__ bbuf,
                                               const int* __restrict__ btot,
                                               int* __restrict__ csr,
                                               int* __restrict__ row_off,
                                               float* __restrict__ dinv) {
  __shared__ int hist[256], off[256], cur[256], sm[256];
  int b = blockIdx.x, t = threadIdx.x;
  // bucket base = exclusive scan of btot at b (in-LDS, threads<256)
  if (t < 256) {
    int v = (t < NBUCK) ? btot[t] : 0;
    sm[t] = v;
    hist[t] = 0; cur[t] = 0;
  }
  __syncthreads();
  for (int o = 1; o < 256; o <<= 1) {
    int add = 0;
    if (t < 256 && t >= o) add = sm[t - o];
    __syncthreads();
    if (t < 256) sm[t] += add;
    __syncthreads();
  }
  int gb = (b > 0) ? sm[b - 1] : 0;
  int cnt = btot[b];
  const unsigned* bp = bbuf + gb;
  for (int i = t; i < cnt; i += 512) atomicAdd(&hist[bp[i] >> 24], 1);
  __syncthreads();
  if (t < 256) off[t] = hist[t];
  __syncthreads();
  for (int o = 1; o < 256; o <<= 1) {
    int add = 0;
    if (t < 256 && t >= o) add = off[t - o];
    __syncthreads();
    if (t < 256) off[t] += add;
    __syncthreads();
  }
  if (t < 256) {
    int excl = off[t] - hist[t];
    off[t] = excl;
    int idx = (b << 8) + t;
    if (idx <= N_NODES) row_off[idx] = gb + excl;
    if (idx < N_NODES)  dinv[idx] = rsqrtf((float)(hist[t] + 1));  // +1 self-loop
  }
  __syncthreads();
  for (int i = t; i < cnt; i += 512) {
    unsigned v = bp[i];
    int ld = v >> 24;
    int pos = atomicAdd(&cur[ld], 1);
    csr[gb + off[ld] + pos] = (int)(v & 0xFFFFFFu);
  }
}

// out_bf16[i][c] = bf16( (x[i,:] @ W[:,c]) * dinv[i] )
// Block = 256 thr = 4 waves; K-step=64 blocking keeps LDS ~34KB -> 4 blk/CU.
template <int K>
__global__ __launch_bounds__(256) void k_gemm(const float* __restrict__ x,
                                              const float* __restrict__ W,
                                              const float* __restrict__ dinv,
                                              unsigned short* __restrict__ out, int N) {
  constexpr int KS = 64;            // K-step
  constexpr int KP = KS + 4;        // padded xs row stride
  __shared__ float xs[64 * KP];     // 17.4 KB
  __shared__ float Wl[KS * 64];     // 16 KB
  const int t = threadIdx.x;
  const int lane = t & 63;
  const int w = t >> 6;
  const int n0 = blockIdx.x * 64;

  float acc[16];
#pragma unroll
  for (int j = 0; j < 16; ++j) acc[j] = 0.f;

  for (int h = 0; h < K / KS; ++h) {
#pragma unroll
    for (int i = 0; i < KS * 16 / 256; ++i) {
      int li = i * 256 + t;
      float4 v = reinterpret_cast<const float4*>(W + h * KS * 64)[li];
      *reinterpret_cast<float4*>(Wl + li * 4) = v;
    }
#pragma unroll
    for (int i = 0; i < 64 * (KS / 4) / 256; ++i) {
      int li = i * 256 + t;
      int row = li / (KS / 4), c4 = li % (KS / 4);
      int node = n0 + row;
      float4 v = make_float4(0.f, 0.f, 0.f, 0.f);
      if (node < N) v = reinterpret_cast<const float4*>(x + (size_t)node * K + h * KS)[c4];
      *reinterpret_cast<float4*>(xs + row * KP + c4 * 4) = v;
    }
    __syncthreads();

    const float* xr = xs + lane * KP;
    const float* wq = Wl + w * 16;
#pragma unroll 4
    for (int kp = 0; kp < KS / 4; ++kp) {
      float4 xv = *reinterpret_cast<const float4*>(xr + kp * 4);
#pragma unroll
      for (int q = 0; q < 4; ++q) {
        int k = kp * 4 + q;
        float xq = (q == 0) ? xv.x : (q == 1) ? xv.y : (q == 2) ? xv.z : xv.w;
        const float* wk = wq + k * 64;                 // wave-uniform address
        float4 w0 = *reinterpret_cast<const float4*>(wk);
        float4 w1 = *reinterpret_cast<const float4*>(wk + 4);
        float4 w2 = *reinterpret_cast<const float4*>(wk + 8);
        float4 w3 = *reinterpret_cast<const float4*>(wk + 12);
        acc[ 0] = fmaf(xq, w0.x, acc[ 0]);
        acc[ 1] = fmaf(xq, w0.y, acc[ 1]);
        acc[ 2] = fmaf(xq, w0.z, acc[ 2]);
        acc[ 3] = fmaf(xq, w0.w, acc[ 3]);
        acc[ 4] = fmaf(xq, w1.x, acc[ 4]);
        acc[ 5] = fmaf(xq, w1.y, acc[ 5]);
        acc[ 6] = fmaf(xq, w1.z, acc[ 6]);
        acc[ 7] = fmaf(xq, w1.w, acc[ 7]);
        acc[ 8] = fmaf(xq, w2.x, acc[ 8]);
        acc[ 9] = fmaf(xq, w2.y, acc[ 9]);
        acc[10] = fmaf(xq, w2.z, acc[10]);
        acc[11] = fmaf(xq, w2.w, acc[11]);
        acc[12] = fmaf(xq, w3.x, acc[12]);
        acc[13] = fmaf(xq, w3.y, acc[13]);
        acc[14] = fmaf(xq, w3.z, acc[14]);
        acc[15] = fmaf(xq, w3.w, acc[15]);
      }
    }
    __syncthreads();   // before next half restages
  }

  int node = n0 + lane;
  if (node < N) {
    float dv = dinv[node];
    unsigned pk[8];
#pragma unroll
    for (int j = 0; j < 8; ++j) {
      unsigned lo = f2bf(acc[2 * j] * dv);
      unsigned hi = f2bf(acc[2 * j + 1] * dv);
      pk[j] = lo | (hi << 16);
    }
    unsigned* op = reinterpret_cast<unsigned*>(out + (size_t)node * 64 + w * 16);
    *reinterpret_cast<uint4*>(op)     = make_uint4(pk[0], pk[1], pk[2], pk[3]);
    *reinterpret_cast<uint4*>(op + 4) = make_uint4(pk[4], pk[5], pk[6], pk[7]);
  }
}

// out[i][c] = relu( dinv[i]*(hs[i][c] + sum_{s} hs[s][c]) + bias[c] ), hs bf16.
// Dual-row dword gather: lanes 0-31 = edge 2q, lanes 32-63 = edge 2q+1;
// 16 loads in flight cover 32 edges; shfl_xor(32) folds halves at the end.
__global__ __launch_bounds__(256) void k_gather(const unsigned short* __restrict__ hs,
                                                const int* __restrict__ row_off,
                                                const int* __restrict__ csr,
                                                const float* __restrict__ dinv,
                                                const float* __restrict__ bias,
                                                float* __restrict__ out, int N) {
  const int lane = threadIdx.x & 63;
  const int half = lane >> 5;        // which edge of the pair
  const int cl   = lane & 31;        // dword (channel pair) within row
  int wid = blockIdx.x * 4 + (threadIdx.x >> 6);
  int stride = gridDim.x * 4;
  const unsigned* hsd = reinterpret_cast<const unsigned*>(hs);
  float b0 = bias[2 * cl], b1 = bias[2 * cl + 1];
  for (int i = wid; i < N; i += stride) {
    float acc0 = 0.f, acc1 = 0.f;
    {  // self-loop term, counted once (half 0 only)
      unsigned sd = hsd[(((unsigned)i) << 5) + cl];
      if (half == 0) { acc0 = bfLo(sd); acc1 = bfHi(sd); }
    }
    const int s0 = row_off[i], s1 = row_off[i + 1];
    int j = s0;
    for (; j + 32 <= s1; j += 32) {
      int idx[16];
#pragma unroll
      for (int q = 0; q < 16; ++q) idx[q] = csr[j + 2 * q + half];
      unsigned v[16];
#pragma unroll
      for (int q = 0; q < 16; ++q)
        v[q] = hsd[(((unsigned)idx[q]) << 5) + cl];    // 16 x 256B in flight
#pragma unroll
      for (int q = 0; q < 16; ++q) { acc0 += bfLo(v[q]); acc1 += bfHi(v[q]); }
    }
    if (j < s1) {                                      // clamped masked tail
      int idx[16];
      bool ok[16];
#pragma unroll
      for (int q = 0; q < 16; ++q) {
        int e = j + 2 * q + half;
        ok[q] = e < s1;
        idx[q] = csr[min(e, s1 - 1)];
      }
      unsigned v[16];
#pragma unroll
      for (int q = 0; q < 16; ++q)
        v[q] = hsd[(((unsigned)idx[q]) << 5) + cl];
#pragma unroll
      for (int q = 0; q < 16; ++q) {
        if (ok[q]) { acc0 += bfLo(v[q]); acc1 += bfHi(v[q]); }
      }
    }
    acc0 += __shfl_xor(acc0, 32);
    acc1 += __shfl_xor(acc1, 32);
    if (half == 0) {
      float dv = dinv[i];
      float r0 = fmaxf(fmaf(acc0, dv, b0), 0.0f);
      float r1 = fmaxf(fmaf(acc1, dv, b1), 0.0f);
      *reinterpret_cast<float2*>(out + (((size_t)i) << 6) + 2 * cl) = make_float2(r0, r1);
    }
  }
}

// Stage-1 pool: wave handles 16 rows; batch sorted -> graph id wave-uniform;
// one fp32 atomicAdd per segment per channel.
__global__ __launch_bounds__(256) void k_pool1(const float* __restrict__ h,
                                               const int* __restrict__ batch,
                                               float* __restrict__ gsum, int N) {
  int c = threadIdx.x & 63;
  int w = threadIdx.x >> 6;
  int r0 = blockIdx.x * 64 + w * 16;
  if (r0 >= N) return;
  int r1 = min(r0 + 16, N);
  int gprev = batch[r0];
  float acc = 0.f;
  for (int r = r0; r < r1; ++r) {
    int g = batch[r];                        // wave-uniform
    if (g != gprev) { atomicAdd(&gsum[gprev * 64 + c], acc); acc = 0.f; gprev = g; }
    acc += h[(size_t)r * 64 + c];            // coalesced 256B row
  }
  atomicAdd(&gsum[gprev * 64 + c], acc);
}

// Final projection; per-block binary searches replace the k_cnt launch.
__global__ void k_final(const float* __restrict__ gsum, const int* __restrict__ batch,
                        const float* __restrict__ Wp, const float* __restrict__ bp,
                        float* __restrict__ out, int N) {
  __shared__ int lb[5];
  int t = threadIdx.x;
  int g0 = blockIdx.x * 4;
  if (t < 5) lb[t] = lowerb(batch, N, g0 + t);
  __syncthreads();
  int idx = blockIdx.x * 256 + t;
  int g = idx >> 6, o = idx & 63, gl = g & 3;
  float cinv = 1.0f / fmaxf((float)(lb[gl + 1] - lb[gl]), 1.0f);
  float acc = 0.f;
#pragma unroll
  for (int k = 0; k < 64; ++k) acc += gsum[g * 64 + k] * Wp[k * 64 + o];
  out[idx] = fmaf(acc, cinv, bp[o]);
}

extern "C" void kernel_launch(void* const* d_in, const int* in_sizes, int n_in,
                              void* d_out, int out_size, void* d_ws, size_t ws_size,
                              hipStream_t stream) {
  const float* x    = (const float*)d_in[0];
  const float* W1   = (const float*)d_in[1];
  const float* b1   = (const float*)d_in[2];
  const float* W2   = (const float*)d_in[3];
  const float* b2   = (const float*)d_in[4];
  const float* Wp   = (const float*)d_in[5];
  const float* bp   = (const float*)d_in[6];
  const int*   ei   = (const int*)d_in[7];
  const int*   batch= (const int*)d_in[8];
  float* out = (float*)d_out;

  const int N = N_NODES, E = N_EDGESC;
  const int* src  = ei;        // edge_index[0]
  const int* dstp = ei + E;    // edge_index[1]

  char* wsb = (char*)d_ws;
  size_t o = 0;
  auto alloc = [&](size_t bytes) -> void* {
    void* p = wsb + o;
    o = (o + bytes + 255) & ~(size_t)255;
    return p;
  };
  int*      bcnt   = (int*)alloc((size_t)NBUCK * NBLK * 4);
  int*      btot   = (int*)alloc(NBUCK * 4);
  unsigned* bbuf   = (unsigned*)alloc((size_t)E * 4);
  int*      row_off= (int*)alloc((size_t)(N + 1) * 4);
  int*      csr    = (int*)alloc((size_t)E * 4);
  float*    dinv   = (float*)alloc((size_t)N * 4);
  unsigned short* bufBF = (unsigned short*)alloc((size_t)N * 64 * 2);
  float*    bufF   = (float*)alloc((size_t)N * 64 * 4);
  float*    gsum   = (float*)alloc(64 * 64 * 4);

  int gN64 = (N + 63) / 64;           // 782

  k_hist<<<NBLK, 256, 0, stream>>>(dstp, bcnt, gsum, E);
  k_cscan<<<NBUCK, 256, 0, stream>>>(bcnt, btot);
  k_scatter<<<NBLK, 256, 0, stream>>>(src, dstp, bcnt, btot, bbuf, E);
  k_bsort<<<NBUCK, 512, 0, stream>>>(bbuf, btot, csr, row_off, dinv);

  k_gemm<128><<<gN64, 256, 0, stream>>>(x, W1, dinv, bufBF, N);
  k_gather<<<2048, 256, 0, stream>>>(bufBF, row_off, csr, dinv, b1, bufF, N);
  k_gemm<64><<<gN64, 256, 0, stream>>>(bufF, W2, dinv, bufBF, N);
  k_gather<<<2048, 256, 0, stream>>>(bufBF, row_off, csr, dinv, b2, bufF, N);

  k_pool1<<<gN64, 256, 0, stream>>>(bufF, batch, gsum, N);
  k_final<<<16, 256, 0, stream>>>(gsum, batch, Wp, bp, out, N);
}

// Round 10
// 160.796 us; speedup vs baseline: 3.4970x; 1.0768x over previous
//
#include <hip/hip_runtime.h>

#define N_NODES  50000
#define N_EDGESC 1600000
#define N_GRAPHS 64
#define NBUCK    196      // ceil(50000/256) buckets of 256 dst nodes
#define CHUNK    2048     // edges per hist/scatter block
#define NBLK     782      // ceil(E/CHUNK)

static __device__ __forceinline__ unsigned short f2bf(float f) {
  unsigned u = __float_as_uint(f);
  u += 0x7FFF + ((u >> 16) & 1);          // RNE
  return (unsigned short)(u >> 16);
}
static __device__ __forceinline__ float bfLo(unsigned u) {
  return __uint_as_float(u << 16);
}
static __device__ __forceinline__ float bfHi(unsigned u) {
  return __uint_as_float(u & 0xFFFF0000u);
}

static __device__ __forceinline__ int lowerb(const int* a, int n, int v) {
  int lo = 0, hi = n;
  while (lo < hi) { int m = (lo + hi) >> 1; if (a[m] < v) lo = m + 1; else hi = m; }
  return lo;
}

// Pass 1: per-block bucket histogram (LDS only) -> bcnt[bucket][blk].
// Block 0 also zeros gsum.
__global__ __launch_bounds__(256) void k_hist(const int* __restrict__ dst,
                                              int* __restrict__ bcnt,
                                              float* __restrict__ gsum, int E) {
  __shared__ int hist[NBUCK];
  int t = threadIdx.x, blk = blockIdx.x;
  if (t < NBUCK) hist[t] = 0;
  if (blk == 0) {
    for (int i = t; i < N_GRAPHS * 64; i += 256) gsum[i] = 0.f;
  }
  __syncthreads();
  int e0 = blk * CHUNK;
#pragma unroll
  for (int i = 0; i < CHUNK; i += 256) {
    int e = e0 + i + t;
    if (e < E) atomicAdd(&hist[dst[e] >> 8], 1);
  }
  __syncthreads();
  if (t < NBUCK) bcnt[(size_t)t * NBLK + blk] = hist[t];
}

// Pass 2: per-bucket exclusive scan across blocks (in place) + bucket totals.
__global__ __launch_bounds__(256) void k_cscan(int* __restrict__ bcnt,
                                               int* __restrict__ btot) {
  __shared__ int sm[256];
  int b = blockIdx.x, t = threadIdx.x;
  int* p = bcnt + (size_t)b * NBLK;
  int carry = 0;
  for (int tile = 0; tile < (NBLK + 255) / 256; ++tile) {
    int idx = tile * 256 + t;
    int v = (idx < NBLK) ? p[idx] : 0;
    sm[t] = v;
    __syncthreads();
    for (int o = 1; o < 256; o <<= 1) {
      int add = (t >= o) ? sm[t - o] : 0;
      __syncthreads();
      sm[t] += add;
      __syncthreads();
    }
    int incl = sm[t];
    int total = sm[255];
    if (idx < NBLK) p[idx] = incl - v + carry;
    carry += total;
    __syncthreads();
  }
  if (t == 0) btot[b] = carry;
}

// Pass 3: scatter edges to final bucket-contiguous positions.
__global__ __launch_bounds__(256) void k_scatter(const int* __restrict__ src,
                                                 const int* __restrict__ dst,
                                                 const int* __restrict__ bcnt,
                                                 const int* __restrict__ btot,
                                                 unsigned* __restrict__ bbuf, int E) {
  __shared__ int base[NBUCK], cur[NBUCK], sm[256];
  int t = threadIdx.x, blk = blockIdx.x;
  int v = (t < NBUCK) ? btot[t] : 0;
  sm[t] = v;
  __syncthreads();
  for (int o = 1; o < 256; o <<= 1) {
    int add = (t >= o) ? sm[t - o] : 0;
    __syncthreads();
    sm[t] += add;
    __syncthreads();
  }
  if (t < NBUCK) {
    base[t] = (sm[t] - v) + bcnt[(size_t)t * NBLK + blk];
    cur[t] = 0;
  }
  __syncthreads();
  int e0 = blk * CHUNK;
#pragma unroll
  for (int i = 0; i < CHUNK; i += 256) {
    int e = e0 + i + t;
    if (e < E) {
      int d = dst[e], b = d >> 8;
      int pos = base[b] + atomicAdd(&cur[b], 1);
      bbuf[pos] = ((unsigned)(d & 255) << 24) | (unsigned)src[e];
    }
  }
}

// Pass 4: per-bucket counting sort -> csr + row_off + dinv. 512 threads.
__global__ __launch_bounds__(512) void k_bsort(const unsigned* __restrict__ bbuf,
                                               const int* __restrict__ btot,
                                               int* __restrict__ csr,
                                               int* __restrict__ row_off,
                                               float* __restrict__ dinv) {
  __shared__ int hist[256], off[256], cur[256], sm[256];
  int b = blockIdx.x, t = threadIdx.x;
  if (t < 256) {
    int v = (t < NBUCK) ? btot[t] : 0;
    sm[t] = v;
    hist[t] = 0; cur[t] = 0;
  }
  __syncthreads();
  for (int o = 1; o < 256; o <<= 1) {
    int add = 0;
    if (t < 256 && t >= o) add = sm[t - o];
    __syncthreads();
    if (t < 256) sm[t] += add;
    __syncthreads();
  }
  int gb = (b > 0) ? sm[b - 1] : 0;
  int cnt = btot[b];
  const unsigned* bp = bbuf + gb;
  for (int i = t; i < cnt; i += 512) atomicAdd(&hist[bp[i] >> 24], 1);
  __syncthreads();
  if (t < 256) off[t] = hist[t];
  __syncthreads();
  for (int o = 1; o < 256; o <<= 1) {
    int add = 0;
    if (t < 256 && t >= o) add = off[t - o];
    __syncthreads();
    if (t < 256) off[t] += add;
    __syncthreads();
  }
  if (t < 256) {
    int excl = off[t] - hist[t];
    off[t] = excl;
    int idx = (b << 8) + t;
    if (idx <= N_NODES) row_off[idx] = gb + excl;
    if (idx < N_NODES)  dinv[idx] = rsqrtf((float)(hist[t] + 1));  // +1 self-loop
  }
  __syncthreads();
  for (int i = t; i < cnt; i += 512) {
    unsigned v = bp[i];
    int ld = v >> 24;
    int pos = atomicAdd(&cur[ld], 1);
    csr[gb + off[ld] + pos] = (int)(v & 0xFFFFFFu);
  }
}

// out_bf16[i][c] = bf16( (x[i,:] @ W[:,c]) * dinv[i] )
template <int K>
__global__ __launch_bounds__(256) void k_gemm(const float* __restrict__ x,
                                              const float* __restrict__ W,
                                              const float* __restrict__ dinv,
                                              unsigned short* __restrict__ out, int N) {
  constexpr int KS = 64;            // K-step
  constexpr int KP = KS + 4;        // padded xs row stride
  __shared__ float xs[64 * KP];     // 17.4 KB
  __shared__ float Wl[KS * 64];     // 16 KB
  const int t = threadIdx.x;
  const int lane = t & 63;
  const int w = t >> 6;
  const int n0 = blockIdx.x * 64;

  float acc[16];
#pragma unroll
  for (int j = 0; j < 16; ++j) acc[j] = 0.f;

  for (int h = 0; h < K / KS; ++h) {
#pragma unroll
    for (int i = 0; i < KS * 16 / 256; ++i) {
      int li = i * 256 + t;
      float4 v = reinterpret_cast<const float4*>(W + h * KS * 64)[li];
      *reinterpret_cast<float4*>(Wl + li * 4) = v;
    }
#pragma unroll
    for (int i = 0; i < 64 * (KS / 4) / 256; ++i) {
      int li = i * 256 + t;
      int row = li / (KS / 4), c4 = li % (KS / 4);
      int node = n0 + row;
      float4 v = make_float4(0.f, 0.f, 0.f, 0.f);
      if (node < N) v = reinterpret_cast<const float4*>(x + (size_t)node * K + h * KS)[c4];
      *reinterpret_cast<float4*>(xs + row * KP + c4 * 4) = v;
    }
    __syncthreads();

    const float* xr = xs + lane * KP;
    const float* wq = Wl + w * 16;
#pragma unroll 4
    for (int kp = 0; kp < KS / 4; ++kp) {
      float4 xv = *reinterpret_cast<const float4*>(xr + kp * 4);
#pragma unroll
      for (int q = 0; q < 4; ++q) {
        int k = kp * 4 + q;
        float xq = (q == 0) ? xv.x : (q == 1) ? xv.y : (q == 2) ? xv.z : xv.w;
        const float* wk = wq + k * 64;                 // wave-uniform address
        float4 w0 = *reinterpret_cast<const float4*>(wk);
        float4 w1 = *reinterpret_cast<const float4*>(wk + 4);
        float4 w2 = *reinterpret_cast<const float4*>(wk + 8);
        float4 w3 = *reinterpret_cast<const float4*>(wk + 12);
        acc[ 0] = fmaf(xq, w0.x, acc[ 0]);
        acc[ 1] = fmaf(xq, w0.y, acc[ 1]);
        acc[ 2] = fmaf(xq, w0.z, acc[ 2]);
        acc[ 3] = fmaf(xq, w0.w, acc[ 3]);
        acc[ 4] = fmaf(xq, w1.x, acc[ 4]);
        acc[ 5] = fmaf(xq, w1.y, acc[ 5]);
        acc[ 6] = fmaf(xq, w1.z, acc[ 6]);
        acc[ 7] = fmaf(xq, w1.w, acc[ 7]);
        acc[ 8] = fmaf(xq, w2.x, acc[ 8]);
        acc[ 9] = fmaf(xq, w2.y, acc[ 9]);
        acc[10] = fmaf(xq, w2.z, acc[10]);
        acc[11] = fmaf(xq, w2.w, acc[11]);
        acc[12] = fmaf(xq, w3.x, acc[12]);
        acc[13] = fmaf(xq, w3.y, acc[13]);
        acc[14] = fmaf(xq, w3.z, acc[14]);
        acc[15] = fmaf(xq, w3.w, acc[15]);
      }
    }
    __syncthreads();   // before next half restages
  }

  int node = n0 + lane;
  if (node < N) {
    float dv = dinv[node];
    unsigned pk[8];
#pragma unroll
    for (int j = 0; j < 8; ++j) {
      unsigned lo = f2bf(acc[2 * j] * dv);
      unsigned hi = f2bf(acc[2 * j + 1] * dv);
      pk[j] = lo | (hi << 16);
    }
    unsigned* op = reinterpret_cast<unsigned*>(out + (size_t)node * 64 + w * 16);
    *reinterpret_cast<uint4*>(op)     = make_uint4(pk[0], pk[1], pk[2], pk[3]);
    *reinterpret_cast<uint4*>(op + 4) = make_uint4(pk[4], pk[5], pk[6], pk[7]);
  }
}

// out[i][c] = relu( dinv[i]*(hs[i][c] + sum_{s} hs[s][c]) + bias[c] ), hs bf16.
// Slot/pos gather: lane = (slot=lane>>3, pos=lane&7). 8 lanes cover one
// 128B row via uint4; 64 lanes = 8 edges per VMEM instruction (1KB).
// Slot-fold (shfl_xor 8/16/32) once per node. Unroll 4 batches -> 32 edges.
__global__ __launch_bounds__(256) void k_gather(const unsigned short* __restrict__ hs,
                                                const int* __restrict__ row_off,
                                                const int* __restrict__ csr,
                                                const float* __restrict__ dinv,
                                                const float* __restrict__ bias,
                                                float* __restrict__ out, int N) {
  const int lane = threadIdx.x & 63;
  const int slot = lane >> 3;        // edge slot (8 edges per instruction)
  const int pos  = lane & 7;         // 16B chunk within 128B row
  int wid = blockIdx.x * 4 + (threadIdx.x >> 6);
  int stride = gridDim.x * 4;
  const uint4* hsq = reinterpret_cast<const uint4*>(hs);
  // this lane's 8 output channels: pos*8 .. pos*8+8
  float4 bA = reinterpret_cast<const float4*>(bias)[pos * 2];
  float4 bB = reinterpret_cast<const float4*>(bias)[pos * 2 + 1];
  for (int i = wid; i < N; i += stride) {
    float a[8];
    {  // self-loop: count once (slot 0 only)
      uint4 sv = hsq[(((unsigned)i) << 3) + pos];
      if (slot == 0) {
        a[0] = bfLo(sv.x); a[1] = bfHi(sv.x); a[2] = bfLo(sv.y); a[3] = bfHi(sv.y);
        a[4] = bfLo(sv.z); a[5] = bfHi(sv.z); a[6] = bfLo(sv.w); a[7] = bfHi(sv.w);
      } else {
#pragma unroll
        for (int k = 0; k < 8; ++k) a[k] = 0.f;
      }
    }
    const int s0 = row_off[i], s1 = row_off[i + 1];
    int j = s0;
    for (; j + 32 <= s1; j += 32) {
      int idx[4];
#pragma unroll
      for (int q = 0; q < 4; ++q) idx[q] = csr[j + 8 * q + slot];
      uint4 v[4];
#pragma unroll
      for (int q = 0; q < 4; ++q)
        v[q] = hsq[(((unsigned)idx[q]) << 3) + pos];   // 4x1KB in flight
#pragma unroll
      for (int q = 0; q < 4; ++q) {
        a[0] += bfLo(v[q].x); a[1] += bfHi(v[q].x);
        a[2] += bfLo(v[q].y); a[3] += bfHi(v[q].y);
        a[4] += bfLo(v[q].z); a[5] += bfHi(v[q].z);
        a[6] += bfLo(v[q].w); a[7] += bfHi(v[q].w);
      }
    }
    if (j < s1) {                                      // clamped masked tail
      int idx[4];
      bool ok[4];
#pragma unroll
      for (int q = 0; q < 4; ++q) {
        int e = j + 8 * q + slot;
        ok[q] = e < s1;
        idx[q] = csr[min(e, s1 - 1)];
      }
      uint4 v[4];
#pragma unroll
      for (int q = 0; q < 4; ++q)
        v[q] = hsq[(((unsigned)idx[q]) << 3) + pos];
#pragma unroll
      for (int q = 0; q < 4; ++q) {
        if (ok[q]) {
          a[0] += bfLo(v[q].x); a[1] += bfHi(v[q].x);
          a[2] += bfLo(v[q].y); a[3] += bfHi(v[q].y);
          a[4] += bfLo(v[q].z); a[5] += bfHi(v[q].z);
          a[6] += bfLo(v[q].w); a[7] += bfHi(v[q].w);
        }
      }
    }
    // fold across 8 slots
#pragma unroll
    for (int k = 0; k < 8; ++k) {
      a[k] += __shfl_xor(a[k], 8);
      a[k] += __shfl_xor(a[k], 16);
      a[k] += __shfl_xor(a[k], 32);
    }
    if (slot == 0) {
      float dv = dinv[i];
      float4 rA, rB;
      rA.x = fmaxf(fmaf(a[0], dv, bA.x), 0.f);
      rA.y = fmaxf(fmaf(a[1], dv, bA.y), 0.f);
      rA.z = fmaxf(fmaf(a[2], dv, bA.z), 0.f);
      rA.w = fmaxf(fmaf(a[3], dv, bA.w), 0.f);
      rB.x = fmaxf(fmaf(a[4], dv, bB.x), 0.f);
      rB.y = fmaxf(fmaf(a[5], dv, bB.y), 0.f);
      rB.z = fmaxf(fmaf(a[6], dv, bB.z), 0.f);
      rB.w = fmaxf(fmaf(a[7], dv, bB.w), 0.f);
      float4* op = reinterpret_cast<float4*>(out + (((size_t)i) << 6) + pos * 8);
      op[0] = rA;
      op[1] = rB;
    }
  }
}

// Stage-1 pool: wave handles 16 rows; batch sorted -> graph id wave-uniform;
// one fp32 atomicAdd per segment per channel.
__global__ __launch_bounds__(256) void k_pool1(const float* __restrict__ h,
                                               const int* __restrict__ batch,
                                               float* __restrict__ gsum, int N) {
  int c = threadIdx.x & 63;
  int w = threadIdx.x >> 6;
  int r0 = blockIdx.x * 64 + w * 16;
  if (r0 >= N) return;
  int r1 = min(r0 + 16, N);
  int gprev = batch[r0];
  float acc = 0.f;
  for (int r = r0; r < r1; ++r) {
    int g = batch[r];                        // wave-uniform
    if (g != gprev) { atomicAdd(&gsum[gprev * 64 + c], acc); acc = 0.f; gprev = g; }
    acc += h[(size_t)r * 64 + c];            // coalesced 256B row
  }
  atomicAdd(&gsum[gprev * 64 + c], acc);
}

// Final projection; per-block binary searches for segment sizes.
__global__ void k_final(const float* __restrict__ gsum, const int* __restrict__ batch,
                        const float* __restrict__ Wp, const float* __restrict__ bp,
                        float* __restrict__ out, int N) {
  __shared__ int lb[5];
  int t = threadIdx.x;
  int g0 = blockIdx.x * 4;
  if (t < 5) lb[t] = lowerb(batch, N, g0 + t);
  __syncthreads();
  int idx = blockIdx.x * 256 + t;
  int g = idx >> 6, o = idx & 63, gl = g & 3;
  float cinv = 1.0f / fmaxf((float)(lb[gl + 1] - lb[gl]), 1.0f);
  float acc = 0.f;
#pragma unroll
  for (int k = 0; k < 64; ++k) acc += gsum[g * 64 + k] * Wp[k * 64 + o];
  out[idx] = fmaf(acc, cinv, bp[o]);
}

extern "C" void kernel_launch(void* const* d_in, const int* in_sizes, int n_in,
                              void* d_out, int out_size, void* d_ws, size_t ws_size,
                              hipStream_t stream) {
  const float* x    = (const float*)d_in[0];
  const float* W1   = (const float*)d_in[1];
  const float* b1   = (const float*)d_in[2];
  const float* W2   = (const float*)d_in[3];
  const float* b2   = (const float*)d_in[4];
  const float* Wp   = (const float*)d_in[5];
  const float* bp   = (const float*)d_in[6];
  const int*   ei   = (const int*)d_in[7];
  const int*   batch= (const int*)d_in[8];
  float* out = (float*)d_out;

  const int N = N_NODES, E = N_EDGESC;
  const int* src  = ei;        // edge_index[0]
  const int* dstp = ei + E;    // edge_index[1]

  char* wsb = (char*)d_ws;
  size_t o = 0;
  auto alloc = [&](size_t bytes) -> void* {
    void* p = wsb + o;
    o = (o + bytes + 255) & ~(size_t)255;
    return p;
  };
  int*      bcnt   = (int*)alloc((size_t)NBUCK * NBLK * 4);
  int*      btot   = (int*)alloc(NBUCK * 4);
  unsigned* bbuf   = (unsigned*)alloc((size_t)E * 4);
  int*      row_off= (int*)alloc((size_t)(N + 1) * 4);
  int*      csr    = (int*)alloc((size_t)E * 4);
  float*    dinv   = (float*)alloc((size_t)N * 4);
  unsigned short* bufBF = (unsigned short*)alloc((size_t)N * 64 * 2);
  float*    bufF   = (float*)alloc((size_t)N * 64 * 4);
  float*    gsum   = (float*)alloc(64 * 64 * 4);

  int gN64 = (N + 63) / 64;           // 782

  k_hist<<<NBLK, 256, 0, stream>>>(dstp, bcnt, gsum, E);
  k_cscan<<<NBUCK, 256, 0, stream>>>(bcnt, btot);
  k_scatter<<<NBLK, 256, 0, stream>>>(src, dstp, bcnt, btot, bbuf, E);
  k_bsort<<<NBUCK, 512, 0, stream>>>(bbuf, btot, csr, row_off, dinv);

  k_gemm<128><<<gN64, 256, 0, stream>>>(x, W1, dinv, bufBF, N);
  k_gather<<<2048, 256, 0, stream>>>(bufBF, row_off, csr, dinv, b1, bufF, N);
  k_gemm<64><<<gN64, 256, 0, stream>>>(bufF, W2, dinv, bufBF, N);
  k_gather<<<2048, 256, 0, stream>>>(bufBF, row_off, csr, dinv, b2, bufF, N);

  k_pool1<<<gN64, 256, 0, stream>>>(bufF, batch, gsum, N);
  k_final<<<16, 256, 0, stream>>>(gsum, batch, Wp, bp, out, N);
}